// Round 19
// baseline (76.313 us; speedup 1.0000x reference)
//
#include <hip/hip_runtime.h>
#include <hip/hip_bf16.h>
#include <stdint.h>

#define N_TOK 8192
#define D 128
#define QTILES (N_TOK / 16)    // 512
#define KVB 64                 // kv rows per staged tile
#define KVTILES (N_TOK / KVB)  // 128
#define LOG2E 1.4426950408889634f

typedef __attribute__((ext_vector_type(8))) short short8;      // 8x16b frag
typedef __attribute__((ext_vector_type(4))) short short4v;     // 4x16b (8B)
typedef __attribute__((ext_vector_type(4))) float f32x4;       // MFMA accum
typedef __attribute__((ext_vector_type(8))) _Float16 half8;    // f16x8 frag
typedef __attribute__((ext_vector_type(4))) _Float16 half4;    // 4 f16 (8B)
typedef __attribute__((ext_vector_type(2))) __fp16 fp16x2;     // cvt_pkrtz ret

__device__ __forceinline__ f32x4 zero4() {
    f32x4 z; z[0] = 0.f; z[1] = 0.f; z[2] = 0.f; z[3] = 0.f; return z;
}
__device__ __forceinline__ float ex2(float x) {
    return __builtin_amdgcn_exp2f(x);   // raw v_exp_f32 (2^x), no libm wrapper
}
__device__ __forceinline__ float max16(const f32x4* s) {
    // 16-value max via v_max3 fusion (nested triples)
    float a = fmaxf(fmaxf(s[0][0], s[0][1]), s[0][2]);
    float b = fmaxf(fmaxf(s[0][3], s[1][0]), s[1][1]);
    float c = fmaxf(fmaxf(s[1][2], s[1][3]), s[2][0]);
    float d = fmaxf(fmaxf(s[2][1], s[2][2]), s[2][3]);
    float e = fmaxf(fmaxf(s[3][0], s[3][1]), s[3][2]);
    return fmaxf(fmaxf(fmaxf(a, b), c), fmaxf(fmaxf(d, e), s[3][3]));
}

// -------- kernel 1: f32 -> f16 convert (weights only; X converted in proj) --
__global__ void cvt_kernel(const float* __restrict__ Wq, const float* __restrict__ Wk,
                           const float* __restrict__ Wv, ushort* __restrict__ Wf) {
    int i = blockIdx.x * blockDim.x + threadIdx.x;
    int w = i * 4;
    if (w >= 3 * 16384) return;
    int m = w >> 14;
    int off = w & 16383;
    const float* src = (m == 0) ? Wq : ((m == 1) ? Wk : Wv);
    ushort* dst = Wf + (m << 14);
    f32x4 v = *(const f32x4*)(src + off);
    half4 pk;
    #pragma unroll
    for (int r = 0; r < 4; ++r) pk[r] = (_Float16)v[r];   // RTN
    *(half4*)(dst + off) = pk;
}

// -------- kernel 2: projections, 512 blocks x 16 q-rows, 2 blocks/CU --------
// Wave w handles jt in {2w, 2w+1} for Q, K, V (single q-subtile per block).
// Q pre-scaled by log2(e) so flash softmax runs in exp2 domain.
__global__ __launch_bounds__(256) void proj_kernel(
    const float* __restrict__ X, const ushort* __restrict__ Wf,
    ushort* __restrict__ Qh, ushort* __restrict__ Kh, ushort* __restrict__ Vt) {
    const int tid = threadIdx.x;
    const int lane = tid & 63;
    const int wid = tid >> 6;
    const int g = lane >> 4, r16 = lane & 15;
    const int qbase = blockIdx.x * 16;

    half8 xf[4];
    {
        const float* xr = X + (size_t)(qbase + r16) * D + 8 * g;
        #pragma unroll
        for (int ds = 0; ds < 4; ++ds) {
            f32x4 a = *(const f32x4*)(xr + 32 * ds);
            f32x4 b = *(const f32x4*)(xr + 32 * ds + 4);
            #pragma unroll
            for (int j = 0; j < 4; ++j) {
                xf[ds][j] = (_Float16)a[j];       // RTN
                xf[ds][4 + j] = (_Float16)b[j];
            }
        }
    }

    #pragma unroll
    for (int m = 0; m < 2; ++m) {
        const ushort* W = Wf + m * 16384;
        ushort* O = m ? Kh : Qh;
        const float sc = m ? 1.0f : LOG2E;
        #pragma unroll
        for (int jj = 0; jj < 2; ++jj) {
            int jt = 2 * wid + jj;
            const ushort* wr = W + (size_t)(16 * jt + r16) * D + 8 * g;
            f32x4 acc = zero4();
            #pragma unroll
            for (int ds = 0; ds < 4; ++ds) {
                half8 wf = *(const half8*)(wr + 32 * ds);
                acc = __builtin_amdgcn_mfma_f32_16x16x32_f16(wf, xf[ds], acc, 0, 0, 0);
            }
            half4 pk;
            #pragma unroll
            for (int r = 0; r < 4; ++r) pk[r] = (_Float16)(acc[r] * sc);
            *(half4*)(O + (size_t)(qbase + r16) * D + 16 * jt + 4 * g) = pk;
        }
    }
    {
        const ushort* W = Wf + 32768;
        #pragma unroll
        for (int jj = 0; jj < 2; ++jj) {
            int jt = 2 * wid + jj;
            const ushort* wr = W + (size_t)(16 * jt + r16) * D + 8 * g;
            f32x4 acc = zero4();
            #pragma unroll
            for (int ds = 0; ds < 4; ++ds) {
                half8 wf = *(const half8*)(wr + 32 * ds);
                acc = __builtin_amdgcn_mfma_f32_16x16x32_f16(xf[ds], wf, acc, 0, 0, 0);
            }
            half4 pk;
            #pragma unroll
            for (int r = 0; r < 4; ++r) pk[r] = (_Float16)acc[r];
            *(half4*)(Vt + (size_t)(16 * jt + r16) * N_TOK + qbase + 4 * g) = pk;
        }
    }
}

// -------- kernel 3: flash attention, double-buffered K+V LDS (R17-proven) ---
// 4 waves/block, 32 q-rows each. NS=8 -> sp == XCD id (L2-affine K/V).
// Softmax in exp2 domain via raw v_exp_f32; m[] holds log2-units max.
template<int NS>
__global__ __launch_bounds__(256, 2) void flash_kernel(
    const ushort* __restrict__ Qh, const ushort* __restrict__ Kh,
    const ushort* __restrict__ Vt, ushort* __restrict__ Opb, float* __restrict__ ML) {
    __shared__ __align__(16) ushort K_lds[2][KVB * D];   // 2 x 16 KB f16
    __shared__ __align__(16) ushort V_lds[2][D * KVB];   // 2 x 16 KB f16
    __shared__ __align__(16) ushort P_lds[4 * 2048];     // 16 KB f16

    const int tid = threadIdx.x;
    const int lane = tid & 63;
    const int wid = tid >> 6;
    const int g = lane >> 4, r16 = lane & 15;
    const int sp = blockIdx.x % NS;        // == XCD id when NS==8
    const int qg = blockIdx.x / NS;
    const int t0 = (KVTILES * sp) / NS;
    const int t1 = (KVTILES * (sp + 1)) / NS;
    const int qbase = qg * 128 + wid * 32;
    const int pswz = (r16 & 7) << 3;

    half8 qf[2][4];
    #pragma unroll
    for (int qa = 0; qa < 2; ++qa) {
        const ushort* qr = Qh + (size_t)(qbase + 16 * qa + r16) * D + 8 * g;
        #pragma unroll
        for (int ds = 0; ds < 4; ++ds)
            qf[qa][ds] = *(const half8*)(qr + 32 * ds);
    }

    float m[2] = {-INFINITY, -INFINITY}, l[2] = {0.f, 0.f};
    f32x4 o[2][8];
    #pragma unroll
    for (int qa = 0; qa < 2; ++qa)
        #pragma unroll
        for (int dt = 0; dt < 8; ++dt) o[qa][dt] = zero4();

    ushort* P_w = &P_lds[wid * 2048];

    short8 sk[4], sv[4];

    auto LOADT = [&](int it) {
        const int kv = it * KVB;
        #pragma unroll
        for (int rr = 0; rr < 4; ++rr) {
            int idx = tid + 256 * rr;              // [0,1024)
            int row = idx >> 4, seg = idx & 15;
            sk[rr] = *(const short8*)(Kh + (size_t)(kv + row) * D + seg * 8);
        }
        #pragma unroll
        for (int rr = 0; rr < 4; ++rr) {
            int idx = tid + 256 * rr;              // [0,1024)
            int row = idx >> 3, seg = idx & 7;
            sv[rr] = *(const short8*)(Vt + (size_t)row * N_TOK + kv + seg * 8);
        }
    };
    auto WRITET = [&](int b) {
        #pragma unroll
        for (int rr = 0; rr < 4; ++rr) {
            int idx = tid + 256 * rr;
            int row = idx >> 4, seg = idx & 15;
            *(short8*)&K_lds[b][(row * 128 + seg * 8) ^ ((row & 7) << 3)] = sk[rr];
        }
        #pragma unroll
        for (int rr = 0; rr < 4; ++rr) {
            int idx = tid + 256 * rr;
            int row = idx >> 3, seg = idx & 7;
            *(short8*)&V_lds[b][(row * 64 + seg * 8) ^ ((row & 7) << 3)] = sv[rr];
        }
    };

    LOADT(t0);
    WRITET(0);
    __syncthreads();

    int buf = 0;
    for (int it = t0; it < t1; ++it) {
        if (it + 1 < t1) LOADT(it + 1);

        const ushort* kb = K_lds[buf];
        const ushort* vb = V_lds[buf];

        // ---- S^T = K*Q^T (scores in log2 domain via Q pre-scaling)
        f32x4 s[2][4];
        #pragma unroll
        for (int qa = 0; qa < 2; ++qa)
            #pragma unroll
            for (int t = 0; t < 4; ++t) s[qa][t] = zero4();
        __builtin_amdgcn_s_setprio(1);
        #pragma unroll
        for (int t = 0; t < 4; ++t) {
            #pragma unroll
            for (int ds = 0; ds < 4; ++ds) {
                int row = 16 * t + r16;
                half8 kf = *(const half8*)&kb[(row * 128 + 32 * ds + 8 * g) ^ ((row & 7) << 3)];
                #pragma unroll
                for (int qa = 0; qa < 2; ++qa)
                    s[qa][t] = __builtin_amdgcn_mfma_f32_16x16x32_f16(kf, qf[qa][ds], s[qa][t], 0, 0, 0);
            }
        }
        __builtin_amdgcn_s_setprio(0);

        // ---- online softmax (exp2 domain, lane-local per r16)
        #pragma unroll
        for (int qa = 0; qa < 2; ++qa) {
            float tm = max16(s[qa]);
            tm = fmaxf(tm, __shfl_xor(tm, 16));
            tm = fmaxf(tm, __shfl_xor(tm, 32));
            // exact-skip rescale: when no lane's max grew, scale==1 for all
            if (!__all(tm <= m[qa])) {
                float mnew = fmaxf(m[qa], tm);
                float scale = ex2(m[qa] - mnew);
                l[qa] *= scale;
                #pragma unroll
                for (int dt = 0; dt < 8; ++dt) o[qa][dt] *= scale;
                m[qa] = mnew;
            }
            float psum = 0.f;
            #pragma unroll
            for (int t = 0; t < 4; ++t) {
                float p0 = ex2(s[qa][t][0] - m[qa]);
                float p1 = ex2(s[qa][t][1] - m[qa]);
                float p2 = ex2(s[qa][t][2] - m[qa]);
                float p3 = ex2(s[qa][t][3] - m[qa]);
                psum += (p0 + p1) + (p2 + p3);
                union { fp16x2 h[2]; short4v s4; } u;
                u.h[0] = __builtin_amdgcn_cvt_pkrtz(p0, p1);
                u.h[1] = __builtin_amdgcn_cvt_pkrtz(p2, p3);
                *(short4v*)&P_w[(qa * 1024 + r16 * 64 + 16 * t + 4 * g) ^ pswz] = u.s4;
            }
            psum += __shfl_xor(psum, 16);
            psum += __shfl_xor(psum, 32);
            l[qa] += psum;
        }

        // ---- O^T += V^T * P^T : 2 kv-chunks x 8 d-tiles (f16)
        __builtin_amdgcn_s_setprio(1);
        #pragma unroll
        for (int c = 0; c < 2; ++c) {
            half8 pf0 = *(const half8*)&P_w[(r16 * 64 + 32 * c + 8 * g) ^ pswz];
            half8 pf1 = *(const half8*)&P_w[(1024 + r16 * 64 + 32 * c + 8 * g) ^ pswz];
            #pragma unroll
            for (int dt = 0; dt < 8; ++dt) {
                int row = 16 * dt + r16;
                half8 vf = *(const half8*)&vb[(row * 64 + 32 * c + 8 * g) ^ ((row & 7) << 3)];
                o[0][dt] = __builtin_amdgcn_mfma_f32_16x16x32_f16(vf, pf0, o[0][dt], 0, 0, 0);
                o[1][dt] = __builtin_amdgcn_mfma_f32_16x16x32_f16(vf, pf1, o[1][dt], 0, 0, 0);
            }
        }
        __builtin_amdgcn_s_setprio(0);

        if (it + 1 < t1) WRITET(buf ^ 1);
        __syncthreads();
        buf ^= 1;
    }

    // ---- epilogue: partial O (pre-division, f16) + (m[log2], l)
    #pragma unroll
    for (int qa = 0; qa < 2; ++qa) {
        ushort* obase = Opb + ((size_t)sp * N_TOK + qbase + 16 * qa + r16) * D + 4 * g;
        #pragma unroll
        for (int dt = 0; dt < 8; ++dt) {
            half4 pk;
            #pragma unroll
            for (int r = 0; r < 4; ++r) pk[r] = (_Float16)o[qa][dt][r];
            *(half4*)(obase + 16 * dt) = pk;
        }
        if (g == 0) {
            int qt = (qbase + 16 * qa) >> 4;
            float* ml = ML + ((size_t)sp * QTILES + qt) * 32;
            ml[r16] = m[qa];
            ml[16 + r16] = l[qa];
        }
    }
}

// -------- kernel 4: merge the NS KV-split partials (f16, exp2-domain m) -----
template<int NS>
__global__ void merge_kernel(const ushort* __restrict__ Opb, const float* __restrict__ ML,
                             float* __restrict__ out) {
    int i = blockIdx.x * blockDim.x + threadIdx.x;
    int e = i * 4;
    if (e >= N_TOK * D) return;
    int q = e >> 7;
    int qt = q >> 4, qr = q & 15;
    float mv[NS], lv[NS];
    float M = -INFINITY;
    #pragma unroll
    for (int s = 0; s < NS; ++s) {
        const float* ml = ML + ((size_t)s * QTILES + qt) * 32;
        mv[s] = ml[qr];
        lv[s] = ml[16 + qr];
        M = fmaxf(M, mv[s]);
    }
    float L = 0.f, a[NS];
    #pragma unroll
    for (int s = 0; s < NS; ++s) { a[s] = __builtin_amdgcn_exp2f(mv[s] - M); L += a[s] * lv[s]; }
    float inv = 1.f / L;
    f32x4 acc = zero4();
    #pragma unroll
    for (int s = 0; s < NS; ++s) {
        half4 ov = *(const half4*)(Opb + (size_t)s * N_TOK * D + e);
        #pragma unroll
        for (int r = 0; r < 4; ++r) acc[r] += (float)ov[r] * a[s];
    }
    *(f32x4*)(out + e) = acc * inv;
}

extern "C" void kernel_launch(void* const* d_in, const int* in_sizes, int n_in,
                              void* d_out, int out_size, void* d_ws, size_t ws_size,
                              hipStream_t stream) {
    const float* X  = (const float*)d_in[0];
    const float* Wq = (const float*)d_in[1];
    const float* Wk = (const float*)d_in[2];
    const float* Wv = (const float*)d_in[3];
    float* out = (float*)d_out;

    char* ws = (char*)d_ws;
    ushort* Wf  = (ushort*)(ws);                   // 96 KB (f16 weights)
    ushort* Qh  = (ushort*)(ws + 98304);           // 2 MB (f16, pre-scaled log2e)
    ushort* Kh  = (ushort*)(ws + 2195456);         // 2 MB (f16)
    ushort* Vt  = (ushort*)(ws + 4292608);         // 2 MB (f16, transposed)
    ushort* Opb = (ushort*)(ws + 6389760);         // NS * 2 MB (f16 partials)

    const size_t op_off = 6389760;
    const size_t need8 = op_off + (size_t)8 * N_TOK * D * 2 + (size_t)8 * QTILES * 32 * 4;

    cvt_kernel<<<48, 256, 0, stream>>>(Wq, Wk, Wv, Wf);
    proj_kernel<<<512, 256, 0, stream>>>(X, Wf, Qh, Kh, Vt);

    if (ws_size >= need8) {
        float* ML = (float*)(ws + op_off + (size_t)8 * N_TOK * D * 2);
        flash_kernel<8><<<(N_TOK / 128) * 8, 256, 0, stream>>>(Qh, Kh, Vt, Opb, ML);
        merge_kernel<8><<<(N_TOK * D / 4 + 255) / 256, 256, 0, stream>>>(Opb, ML, out);
    } else {
        float* ML = (float*)(ws + op_off + (size_t)4 * N_TOK * D * 2);
        flash_kernel<4><<<(N_TOK / 128) * 4, 256, 0, stream>>>(Qh, Kh, Vt, Opb, ML);
        merge_kernel<4><<<(N_TOK * D / 4 + 255) / 256, 256, 0, stream>>>(Opb, ML, out);
    }
}

// Round 20
// 72.722 us; speedup vs baseline: 1.0494x; 1.0494x over previous
//
#include <hip/hip_runtime.h>
#include <hip/hip_bf16.h>
#include <stdint.h>

#define N_TOK 8192
#define D 128
#define QTILES (N_TOK / 16)    // 512
#define KVB 64                 // kv rows per staged tile
#define KVTILES (N_TOK / KVB)  // 128
#define LOG2E 1.4426950408889634f

typedef __attribute__((ext_vector_type(8))) short short8;      // 8x16b frag
typedef __attribute__((ext_vector_type(4))) short short4v;     // 4x16b (8B)
typedef __attribute__((ext_vector_type(4))) float f32x4;       // MFMA accum
typedef __attribute__((ext_vector_type(8))) _Float16 half8;    // f16x8 frag
typedef __attribute__((ext_vector_type(4))) _Float16 half4;    // 4 f16 (8B)
typedef __attribute__((ext_vector_type(2))) __fp16 fp16x2;     // cvt_pkrtz ret

__device__ __forceinline__ f32x4 zero4() {
    f32x4 z; z[0] = 0.f; z[1] = 0.f; z[2] = 0.f; z[3] = 0.f; return z;
}
__device__ __forceinline__ float ex2(float x) {
    return __builtin_amdgcn_exp2f(x);   // raw v_exp_f32 (2^x), no libm wrapper
}
__device__ __forceinline__ float max16(const f32x4* s) {
    // 16-value max via v_max3 fusion (nested triples)
    float a = fmaxf(fmaxf(s[0][0], s[0][1]), s[0][2]);
    float b = fmaxf(fmaxf(s[0][3], s[1][0]), s[1][1]);
    float c = fmaxf(fmaxf(s[1][2], s[1][3]), s[2][0]);
    float d = fmaxf(fmaxf(s[2][1], s[2][2]), s[2][3]);
    float e = fmaxf(fmaxf(s[3][0], s[3][1]), s[3][2]);
    return fmaxf(fmaxf(fmaxf(a, b), c), fmaxf(fmaxf(d, e), s[3][3]));
}

// -------- kernel 1: f32 -> f16 convert (weights only; X converted in proj) --
__global__ void cvt_kernel(const float* __restrict__ Wq, const float* __restrict__ Wk,
                           const float* __restrict__ Wv, ushort* __restrict__ Wf) {
    int i = blockIdx.x * blockDim.x + threadIdx.x;
    int w = i * 4;
    if (w >= 3 * 16384) return;
    int m = w >> 14;
    int off = w & 16383;
    const float* src = (m == 0) ? Wq : ((m == 1) ? Wk : Wv);
    ushort* dst = Wf + (m << 14);
    f32x4 v = *(const f32x4*)(src + off);
    half4 pk;
    #pragma unroll
    for (int r = 0; r < 4; ++r) pk[r] = (_Float16)v[r];   // RTN
    *(half4*)(dst + off) = pk;
}

// -------- kernel 2: projections, single f16 MFMA (R17-proven) ---------------
// 256 blocks x 4 waves; wave w handles jt in {2w, 2w+1}; qa=2 W-reuse.
// Q pre-scaled by log2(e) so flash softmax runs in exp2 domain.
__global__ __launch_bounds__(256) void proj_kernel(
    const float* __restrict__ X, const ushort* __restrict__ Wf,
    ushort* __restrict__ Qh, ushort* __restrict__ Kh, ushort* __restrict__ Vt) {
    const int tid = threadIdx.x;
    const int lane = tid & 63;
    const int wid = tid >> 6;
    const int g = lane >> 4, r16 = lane & 15;
    const int qbase = blockIdx.x * 32;

    half8 xf[2][4];
    #pragma unroll
    for (int qa = 0; qa < 2; ++qa) {
        const float* xr = X + (size_t)(qbase + 16 * qa + r16) * D + 8 * g;
        #pragma unroll
        for (int ds = 0; ds < 4; ++ds) {
            f32x4 a = *(const f32x4*)(xr + 32 * ds);
            f32x4 b = *(const f32x4*)(xr + 32 * ds + 4);
            #pragma unroll
            for (int j = 0; j < 4; ++j) {
                xf[qa][ds][j] = (_Float16)a[j];       // RTN
                xf[qa][ds][4 + j] = (_Float16)b[j];
            }
        }
    }

    #pragma unroll
    for (int m = 0; m < 2; ++m) {
        const ushort* W = Wf + m * 16384;
        ushort* O = m ? Kh : Qh;
        const float sc = m ? 1.0f : LOG2E;
        #pragma unroll
        for (int jj = 0; jj < 2; ++jj) {
            int jt = 2 * wid + jj;
            const ushort* wr = W + (size_t)(16 * jt + r16) * D + 8 * g;
            f32x4 acc[2] = {zero4(), zero4()};
            #pragma unroll
            for (int ds = 0; ds < 4; ++ds) {
                half8 wf = *(const half8*)(wr + 32 * ds);
                #pragma unroll
                for (int qa = 0; qa < 2; ++qa)
                    acc[qa] = __builtin_amdgcn_mfma_f32_16x16x32_f16(wf, xf[qa][ds], acc[qa], 0, 0, 0);
            }
            #pragma unroll
            for (int qa = 0; qa < 2; ++qa) {
                half4 pk;
                #pragma unroll
                for (int r = 0; r < 4; ++r) pk[r] = (_Float16)(acc[qa][r] * sc);
                *(half4*)(O + (size_t)(qbase + 16 * qa + r16) * D + 16 * jt + 4 * g) = pk;
            }
        }
    }
    {
        const ushort* W = Wf + 32768;
        #pragma unroll
        for (int jj = 0; jj < 2; ++jj) {
            int jt = 2 * wid + jj;
            const ushort* wr = W + (size_t)(16 * jt + r16) * D + 8 * g;
            f32x4 acc[2] = {zero4(), zero4()};
            #pragma unroll
            for (int ds = 0; ds < 4; ++ds) {
                half8 wf = *(const half8*)(wr + 32 * ds);
                #pragma unroll
                for (int qa = 0; qa < 2; ++qa)
                    acc[qa] = __builtin_amdgcn_mfma_f32_16x16x32_f16(xf[qa][ds], wf, acc[qa], 0, 0, 0);
            }
            #pragma unroll
            for (int qa = 0; qa < 2; ++qa) {
                half4 pk;
                #pragma unroll
                for (int r = 0; r < 4; ++r) pk[r] = (_Float16)acc[qa][r];
                *(half4*)(Vt + (size_t)(16 * jt + r16) * N_TOK + qbase + 16 * qa + 4 * g) = pk;
            }
        }
    }
}

// -------- kernel 3: flash attention, double-buffered K+V LDS (R17-proven) ---
// 4 waves/block, 32 q-rows each. NS=8 -> sp == XCD id (L2-affine K/V).
// Softmax in exp2 domain via raw v_exp_f32; m[] holds log2-units max.
template<int NS>
__global__ __launch_bounds__(256, 2) void flash_kernel(
    const ushort* __restrict__ Qh, const ushort* __restrict__ Kh,
    const ushort* __restrict__ Vt, ushort* __restrict__ Opb, float* __restrict__ ML) {
    __shared__ __align__(16) ushort K_lds[2][KVB * D];   // 2 x 16 KB f16
    __shared__ __align__(16) ushort V_lds[2][D * KVB];   // 2 x 16 KB f16
    __shared__ __align__(16) ushort P_lds[4 * 2048];     // 16 KB f16

    const int tid = threadIdx.x;
    const int lane = tid & 63;
    const int wid = tid >> 6;
    const int g = lane >> 4, r16 = lane & 15;
    const int sp = blockIdx.x % NS;        // == XCD id when NS==8
    const int qg = blockIdx.x / NS;
    const int t0 = (KVTILES * sp) / NS;
    const int t1 = (KVTILES * (sp + 1)) / NS;
    const int qbase = qg * 128 + wid * 32;
    const int pswz = (r16 & 7) << 3;

    half8 qf[2][4];
    #pragma unroll
    for (int qa = 0; qa < 2; ++qa) {
        const ushort* qr = Qh + (size_t)(qbase + 16 * qa + r16) * D + 8 * g;
        #pragma unroll
        for (int ds = 0; ds < 4; ++ds)
            qf[qa][ds] = *(const half8*)(qr + 32 * ds);
    }

    float m[2] = {-INFINITY, -INFINITY}, l[2] = {0.f, 0.f};
    f32x4 o[2][8];
    #pragma unroll
    for (int qa = 0; qa < 2; ++qa)
        #pragma unroll
        for (int dt = 0; dt < 8; ++dt) o[qa][dt] = zero4();

    ushort* P_w = &P_lds[wid * 2048];

    short8 sk[4], sv[4];

    auto LOADT = [&](int it) {
        const int kv = it * KVB;
        #pragma unroll
        for (int rr = 0; rr < 4; ++rr) {
            int idx = tid + 256 * rr;              // [0,1024)
            int row = idx >> 4, seg = idx & 15;
            sk[rr] = *(const short8*)(Kh + (size_t)(kv + row) * D + seg * 8);
        }
        #pragma unroll
        for (int rr = 0; rr < 4; ++rr) {
            int idx = tid + 256 * rr;              // [0,1024)
            int row = idx >> 3, seg = idx & 7;
            sv[rr] = *(const short8*)(Vt + (size_t)row * N_TOK + kv + seg * 8);
        }
    };
    auto WRITET = [&](int b) {
        #pragma unroll
        for (int rr = 0; rr < 4; ++rr) {
            int idx = tid + 256 * rr;
            int row = idx >> 4, seg = idx & 15;
            *(short8*)&K_lds[b][(row * 128 + seg * 8) ^ ((row & 7) << 3)] = sk[rr];
        }
        #pragma unroll
        for (int rr = 0; rr < 4; ++rr) {
            int idx = tid + 256 * rr;
            int row = idx >> 3, seg = idx & 7;
            *(short8*)&V_lds[b][(row * 64 + seg * 8) ^ ((row & 7) << 3)] = sv[rr];
        }
    };

    LOADT(t0);
    WRITET(0);
    __syncthreads();

    int buf = 0;
    for (int it = t0; it < t1; ++it) {
        if (it + 1 < t1) LOADT(it + 1);

        const ushort* kb = K_lds[buf];
        const ushort* vb = V_lds[buf];

        // ---- S^T = K*Q^T (scores in log2 domain via Q pre-scaling)
        f32x4 s[2][4];
        #pragma unroll
        for (int qa = 0; qa < 2; ++qa)
            #pragma unroll
            for (int t = 0; t < 4; ++t) s[qa][t] = zero4();
        __builtin_amdgcn_s_setprio(1);
        #pragma unroll
        for (int t = 0; t < 4; ++t) {
            #pragma unroll
            for (int ds = 0; ds < 4; ++ds) {
                int row = 16 * t + r16;
                half8 kf = *(const half8*)&kb[(row * 128 + 32 * ds + 8 * g) ^ ((row & 7) << 3)];
                #pragma unroll
                for (int qa = 0; qa < 2; ++qa)
                    s[qa][t] = __builtin_amdgcn_mfma_f32_16x16x32_f16(kf, qf[qa][ds], s[qa][t], 0, 0, 0);
            }
        }
        __builtin_amdgcn_s_setprio(0);

        // ---- online softmax (exp2 domain, lane-local per r16)
        #pragma unroll
        for (int qa = 0; qa < 2; ++qa) {
            float tm = max16(s[qa]);
            tm = fmaxf(tm, __shfl_xor(tm, 16));
            tm = fmaxf(tm, __shfl_xor(tm, 32));
            // exact-skip rescale: when no lane's max grew, scale==1 for all
            if (!__all(tm <= m[qa])) {
                float mnew = fmaxf(m[qa], tm);
                float scale = ex2(m[qa] - mnew);
                l[qa] *= scale;
                #pragma unroll
                for (int dt = 0; dt < 8; ++dt) o[qa][dt] *= scale;
                m[qa] = mnew;
            }
            float psum = 0.f;
            #pragma unroll
            for (int t = 0; t < 4; ++t) {
                float p0 = ex2(s[qa][t][0] - m[qa]);
                float p1 = ex2(s[qa][t][1] - m[qa]);
                float p2 = ex2(s[qa][t][2] - m[qa]);
                float p3 = ex2(s[qa][t][3] - m[qa]);
                psum += (p0 + p1) + (p2 + p3);
                union { fp16x2 h[2]; short4v s4; } u;
                u.h[0] = __builtin_amdgcn_cvt_pkrtz(p0, p1);
                u.h[1] = __builtin_amdgcn_cvt_pkrtz(p2, p3);
                *(short4v*)&P_w[(qa * 1024 + r16 * 64 + 16 * t + 4 * g) ^ pswz] = u.s4;
            }
            psum += __shfl_xor(psum, 16);
            psum += __shfl_xor(psum, 32);
            l[qa] += psum;
        }

        // ---- O^T += V^T * P^T : 2 kv-chunks x 8 d-tiles (f16)
        __builtin_amdgcn_s_setprio(1);
        #pragma unroll
        for (int c = 0; c < 2; ++c) {
            half8 pf0 = *(const half8*)&P_w[(r16 * 64 + 32 * c + 8 * g) ^ pswz];
            half8 pf1 = *(const half8*)&P_w[(1024 + r16 * 64 + 32 * c + 8 * g) ^ pswz];
            #pragma unroll
            for (int dt = 0; dt < 8; ++dt) {
                int row = 16 * dt + r16;
                half8 vf = *(const half8*)&vb[(row * 64 + 32 * c + 8 * g) ^ ((row & 7) << 3)];
                o[0][dt] = __builtin_amdgcn_mfma_f32_16x16x32_f16(vf, pf0, o[0][dt], 0, 0, 0);
                o[1][dt] = __builtin_amdgcn_mfma_f32_16x16x32_f16(vf, pf1, o[1][dt], 0, 0, 0);
            }
        }
        __builtin_amdgcn_s_setprio(0);

        if (it + 1 < t1) WRITET(buf ^ 1);
        __syncthreads();
        buf ^= 1;
    }

    // ---- epilogue: partial O (pre-division, f16) + (m[log2], l)
    #pragma unroll
    for (int qa = 0; qa < 2; ++qa) {
        ushort* obase = Opb + ((size_t)sp * N_TOK + qbase + 16 * qa + r16) * D + 4 * g;
        #pragma unroll
        for (int dt = 0; dt < 8; ++dt) {
            half4 pk;
            #pragma unroll
            for (int r = 0; r < 4; ++r) pk[r] = (_Float16)o[qa][dt][r];
            *(half4*)(obase + 16 * dt) = pk;
        }
        if (g == 0) {
            int qt = (qbase + 16 * qa) >> 4;
            float* ml = ML + ((size_t)sp * QTILES + qt) * 32;
            ml[r16] = m[qa];
            ml[16 + r16] = l[qa];
        }
    }
}

// -------- kernel 4: merge the NS KV-split partials (16B loads, 8 elem/thr) --
template<int NS>
__global__ void merge_kernel(const ushort* __restrict__ Opb, const float* __restrict__ ML,
                             float* __restrict__ out) {
    int i = blockIdx.x * blockDim.x + threadIdx.x;
    int e = i * 8;
    if (e >= N_TOK * D) return;
    int q = e >> 7;
    int qt = q >> 4, qr = q & 15;
    float mv[NS], lv[NS];
    float M = -INFINITY;
    #pragma unroll
    for (int s = 0; s < NS; ++s) {
        const float* ml = ML + ((size_t)s * QTILES + qt) * 32;
        mv[s] = ml[qr];
        lv[s] = ml[16 + qr];
        M = fmaxf(M, mv[s]);
    }
    float L = 0.f, a[NS];
    #pragma unroll
    for (int s = 0; s < NS; ++s) { a[s] = __builtin_amdgcn_exp2f(mv[s] - M); L += a[s] * lv[s]; }
    float inv = 1.f / L;
    float acc[8];
    #pragma unroll
    for (int r = 0; r < 8; ++r) acc[r] = 0.f;
    #pragma unroll
    for (int s = 0; s < NS; ++s) {
        half8 ov = *(const half8*)(Opb + (size_t)s * N_TOK * D + e);
        #pragma unroll
        for (int r = 0; r < 8; ++r) acc[r] += (float)ov[r] * a[s];
    }
    f32x4 o0, o1;
    #pragma unroll
    for (int r = 0; r < 4; ++r) { o0[r] = acc[r] * inv; o1[r] = acc[4 + r] * inv; }
    *(f32x4*)(out + e) = o0;
    *(f32x4*)(out + e + 4) = o1;
}

extern "C" void kernel_launch(void* const* d_in, const int* in_sizes, int n_in,
                              void* d_out, int out_size, void* d_ws, size_t ws_size,
                              hipStream_t stream) {
    const float* X  = (const float*)d_in[0];
    const float* Wq = (const float*)d_in[1];
    const float* Wk = (const float*)d_in[2];
    const float* Wv = (const float*)d_in[3];
    float* out = (float*)d_out;

    char* ws = (char*)d_ws;
    ushort* Wf  = (ushort*)(ws);                   // 96 KB (f16 weights)
    ushort* Qh  = (ushort*)(ws + 98304);           // 2 MB (f16, pre-scaled log2e)
    ushort* Kh  = (ushort*)(ws + 2195456);         // 2 MB (f16)
    ushort* Vt  = (ushort*)(ws + 4292608);         // 2 MB (f16, transposed)
    ushort* Opb = (ushort*)(ws + 6389760);         // NS * 2 MB (f16 partials)

    const size_t op_off = 6389760;
    const size_t need8 = op_off + (size_t)8 * N_TOK * D * 2 + (size_t)8 * QTILES * 32 * 4;

    cvt_kernel<<<48, 256, 0, stream>>>(Wq, Wk, Wv, Wf);
    proj_kernel<<<256, 256, 0, stream>>>(X, Wf, Qh, Kh, Vt);

    if (ws_size >= need8) {
        float* ML = (float*)(ws + op_off + (size_t)8 * N_TOK * D * 2);
        flash_kernel<8><<<(N_TOK / 128) * 8, 256, 0, stream>>>(Qh, Kh, Vt, Opb, ML);
        merge_kernel<8><<<(N_TOK * D / 8 + 255) / 256, 256, 0, stream>>>(Opb, ML, out);
    } else {
        float* ML = (float*)(ws + op_off + (size_t)4 * N_TOK * D * 2);
        flash_kernel<4><<<(N_TOK / 128) * 4, 256, 0, stream>>>(Qh, Kh, Vt, Opb, ML);
        merge_kernel<4><<<(N_TOK * D / 8 + 255) / 256, 256, 0, stream>>>(Opb, ML, out);
    }
}

// Round 21
// 72.227 us; speedup vs baseline: 1.0566x; 1.0069x over previous
//
#include <hip/hip_runtime.h>
#include <hip/hip_bf16.h>
#include <stdint.h>

#define N_TOK 8192
#define D 128
#define QTILES (N_TOK / 16)    // 512
#define KVB 64                 // kv rows per staged tile
#define KVTILES (N_TOK / KVB)  // 128
#define LOG2E 1.4426950408889634f

typedef __attribute__((ext_vector_type(8))) short short8;      // 8x16b frag
typedef __attribute__((ext_vector_type(4))) short short4v;     // 4x16b (8B)
typedef __attribute__((ext_vector_type(4))) float f32x4;       // MFMA accum
typedef __attribute__((ext_vector_type(8))) _Float16 half8;    // f16x8 frag
typedef __attribute__((ext_vector_type(4))) _Float16 half4;    // 4 f16 (8B)
typedef __attribute__((ext_vector_type(2))) __fp16 fp16x2;     // cvt_pkrtz ret

__device__ __forceinline__ f32x4 zero4() {
    f32x4 z; z[0] = 0.f; z[1] = 0.f; z[2] = 0.f; z[3] = 0.f; return z;
}
__device__ __forceinline__ float ex2(float x) {
    return __builtin_amdgcn_exp2f(x);   // raw v_exp_f32 (2^x), no libm wrapper
}
__device__ __forceinline__ float max16(const f32x4* s) {
    // 16-value max via v_max3 fusion (nested triples)
    float a = fmaxf(fmaxf(s[0][0], s[0][1]), s[0][2]);
    float b = fmaxf(fmaxf(s[0][3], s[1][0]), s[1][1]);
    float c = fmaxf(fmaxf(s[1][2], s[1][3]), s[2][0]);
    float d = fmaxf(fmaxf(s[2][1], s[2][2]), s[2][3]);
    float e = fmaxf(fmaxf(s[3][0], s[3][1]), s[3][2]);
    return fmaxf(fmaxf(fmaxf(a, b), c), fmaxf(fmaxf(d, e), s[3][3]));
}
// load 8 consecutive f32 and convert to f16x8 fragment (RTN)
__device__ __forceinline__ half8 ld_f32_as_h8(const float* p) {
    f32x4 a = *(const f32x4*)(p);
    f32x4 b = *(const f32x4*)(p + 4);
    half8 w;
    #pragma unroll
    for (int j = 0; j < 4; ++j) {
        w[j] = (_Float16)a[j];
        w[4 + j] = (_Float16)b[j];
    }
    return w;
}

// -------- kernel 1: projections, single f16 MFMA, W converted in-register ---
// 256 blocks x 4 waves; wave w handles jt in {2w, 2w+1}; qa=2 W-reuse.
// X and W both f32->f16 RTN at load time (bit-identical to the old cvt path).
// Q pre-scaled by log2(e) so flash softmax runs in exp2 domain.
__global__ __launch_bounds__(256) void proj_kernel(
    const float* __restrict__ X, const float* __restrict__ Wq,
    const float* __restrict__ Wk, const float* __restrict__ Wv,
    ushort* __restrict__ Qh, ushort* __restrict__ Kh, ushort* __restrict__ Vt) {
    const int tid = threadIdx.x;
    const int lane = tid & 63;
    const int wid = tid >> 6;
    const int g = lane >> 4, r16 = lane & 15;
    const int qbase = blockIdx.x * 32;

    half8 xf[2][4];
    #pragma unroll
    for (int qa = 0; qa < 2; ++qa) {
        const float* xr = X + (size_t)(qbase + 16 * qa + r16) * D + 8 * g;
        #pragma unroll
        for (int ds = 0; ds < 4; ++ds)
            xf[qa][ds] = ld_f32_as_h8(xr + 32 * ds);
    }

    #pragma unroll
    for (int m = 0; m < 2; ++m) {
        const float* W = m ? Wk : Wq;
        ushort* O = m ? Kh : Qh;
        const float sc = m ? 1.0f : LOG2E;
        #pragma unroll
        for (int jj = 0; jj < 2; ++jj) {
            int jt = 2 * wid + jj;
            const float* wr = W + (size_t)(16 * jt + r16) * D + 8 * g;
            f32x4 acc[2] = {zero4(), zero4()};
            #pragma unroll
            for (int ds = 0; ds < 4; ++ds) {
                half8 wf = ld_f32_as_h8(wr + 32 * ds);
                #pragma unroll
                for (int qa = 0; qa < 2; ++qa)
                    acc[qa] = __builtin_amdgcn_mfma_f32_16x16x32_f16(wf, xf[qa][ds], acc[qa], 0, 0, 0);
            }
            #pragma unroll
            for (int qa = 0; qa < 2; ++qa) {
                half4 pk;
                #pragma unroll
                for (int r = 0; r < 4; ++r) pk[r] = (_Float16)(acc[qa][r] * sc);
                *(half4*)(O + (size_t)(qbase + 16 * qa + r16) * D + 16 * jt + 4 * g) = pk;
            }
        }
    }
    {
        #pragma unroll
        for (int jj = 0; jj < 2; ++jj) {
            int jt = 2 * wid + jj;
            const float* wr = Wv + (size_t)(16 * jt + r16) * D + 8 * g;
            f32x4 acc[2] = {zero4(), zero4()};
            #pragma unroll
            for (int ds = 0; ds < 4; ++ds) {
                half8 wf = ld_f32_as_h8(wr + 32 * ds);
                #pragma unroll
                for (int qa = 0; qa < 2; ++qa)
                    acc[qa] = __builtin_amdgcn_mfma_f32_16x16x32_f16(xf[qa][ds], wf, acc[qa], 0, 0, 0);
            }
            #pragma unroll
            for (int qa = 0; qa < 2; ++qa) {
                half4 pk;
                #pragma unroll
                for (int r = 0; r < 4; ++r) pk[r] = (_Float16)acc[qa][r];
                *(half4*)(Vt + (size_t)(16 * jt + r16) * N_TOK + qbase + 16 * qa + 4 * g) = pk;
            }
        }
    }
}

// -------- kernel 2: flash attention, double-buffered K+V LDS ----------------
// R17-proven schedule, setprio REMOVED (m190: setprio hurts barrier-synced
// lockstep kernels; only helps phase-diverse waves).
// 4 waves/block, 32 q-rows each. NS=8 -> sp == XCD id (L2-affine K/V).
// Softmax in exp2 domain via raw v_exp_f32; m[] holds log2-units max.
template<int NS>
__global__ __launch_bounds__(256, 2) void flash_kernel(
    const ushort* __restrict__ Qh, const ushort* __restrict__ Kh,
    const ushort* __restrict__ Vt, ushort* __restrict__ Opb, float* __restrict__ ML) {
    __shared__ __align__(16) ushort K_lds[2][KVB * D];   // 2 x 16 KB f16
    __shared__ __align__(16) ushort V_lds[2][D * KVB];   // 2 x 16 KB f16
    __shared__ __align__(16) ushort P_lds[4 * 2048];     // 16 KB f16

    const int tid = threadIdx.x;
    const int lane = tid & 63;
    const int wid = tid >> 6;
    const int g = lane >> 4, r16 = lane & 15;
    const int sp = blockIdx.x % NS;        // == XCD id when NS==8
    const int qg = blockIdx.x / NS;
    const int t0 = (KVTILES * sp) / NS;
    const int t1 = (KVTILES * (sp + 1)) / NS;
    const int qbase = qg * 128 + wid * 32;
    const int pswz = (r16 & 7) << 3;

    half8 qf[2][4];
    #pragma unroll
    for (int qa = 0; qa < 2; ++qa) {
        const ushort* qr = Qh + (size_t)(qbase + 16 * qa + r16) * D + 8 * g;
        #pragma unroll
        for (int ds = 0; ds < 4; ++ds)
            qf[qa][ds] = *(const half8*)(qr + 32 * ds);
    }

    float m[2] = {-INFINITY, -INFINITY}, l[2] = {0.f, 0.f};
    f32x4 o[2][8];
    #pragma unroll
    for (int qa = 0; qa < 2; ++qa)
        #pragma unroll
        for (int dt = 0; dt < 8; ++dt) o[qa][dt] = zero4();

    ushort* P_w = &P_lds[wid * 2048];

    short8 sk[4], sv[4];

    auto LOADT = [&](int it) {
        const int kv = it * KVB;
        #pragma unroll
        for (int rr = 0; rr < 4; ++rr) {
            int idx = tid + 256 * rr;              // [0,1024)
            int row = idx >> 4, seg = idx & 15;
            sk[rr] = *(const short8*)(Kh + (size_t)(kv + row) * D + seg * 8);
        }
        #pragma unroll
        for (int rr = 0; rr < 4; ++rr) {
            int idx = tid + 256 * rr;              // [0,1024)
            int row = idx >> 3, seg = idx & 7;
            sv[rr] = *(const short8*)(Vt + (size_t)row * N_TOK + kv + seg * 8);
        }
    };
    auto WRITET = [&](int b) {
        #pragma unroll
        for (int rr = 0; rr < 4; ++rr) {
            int idx = tid + 256 * rr;
            int row = idx >> 4, seg = idx & 15;
            *(short8*)&K_lds[b][(row * 128 + seg * 8) ^ ((row & 7) << 3)] = sk[rr];
        }
        #pragma unroll
        for (int rr = 0; rr < 4; ++rr) {
            int idx = tid + 256 * rr;
            int row = idx >> 3, seg = idx & 7;
            *(short8*)&V_lds[b][(row * 64 + seg * 8) ^ ((row & 7) << 3)] = sv[rr];
        }
    };

    LOADT(t0);
    WRITET(0);
    __syncthreads();

    int buf = 0;
    for (int it = t0; it < t1; ++it) {
        if (it + 1 < t1) LOADT(it + 1);

        const ushort* kb = K_lds[buf];
        const ushort* vb = V_lds[buf];

        // ---- S^T = K*Q^T (scores in log2 domain via Q pre-scaling)
        f32x4 s[2][4];
        #pragma unroll
        for (int qa = 0; qa < 2; ++qa)
            #pragma unroll
            for (int t = 0; t < 4; ++t) s[qa][t] = zero4();
        #pragma unroll
        for (int t = 0; t < 4; ++t) {
            #pragma unroll
            for (int ds = 0; ds < 4; ++ds) {
                int row = 16 * t + r16;
                half8 kf = *(const half8*)&kb[(row * 128 + 32 * ds + 8 * g) ^ ((row & 7) << 3)];
                #pragma unroll
                for (int qa = 0; qa < 2; ++qa)
                    s[qa][t] = __builtin_amdgcn_mfma_f32_16x16x32_f16(kf, qf[qa][ds], s[qa][t], 0, 0, 0);
            }
        }

        // ---- online softmax (exp2 domain, lane-local per r16)
        #pragma unroll
        for (int qa = 0; qa < 2; ++qa) {
            float tm = max16(s[qa]);
            tm = fmaxf(tm, __shfl_xor(tm, 16));
            tm = fmaxf(tm, __shfl_xor(tm, 32));
            // exact-skip rescale: when no lane's max grew, scale==1 for all
            if (!__all(tm <= m[qa])) {
                float mnew = fmaxf(m[qa], tm);
                float scale = ex2(m[qa] - mnew);
                l[qa] *= scale;
                #pragma unroll
                for (int dt = 0; dt < 8; ++dt) o[qa][dt] *= scale;
                m[qa] = mnew;
            }
            float psum = 0.f;
            #pragma unroll
            for (int t = 0; t < 4; ++t) {
                float p0 = ex2(s[qa][t][0] - m[qa]);
                float p1 = ex2(s[qa][t][1] - m[qa]);
                float p2 = ex2(s[qa][t][2] - m[qa]);
                float p3 = ex2(s[qa][t][3] - m[qa]);
                psum += (p0 + p1) + (p2 + p3);
                union { fp16x2 h[2]; short4v s4; } u;
                u.h[0] = __builtin_amdgcn_cvt_pkrtz(p0, p1);
                u.h[1] = __builtin_amdgcn_cvt_pkrtz(p2, p3);
                *(short4v*)&P_w[(qa * 1024 + r16 * 64 + 16 * t + 4 * g) ^ pswz] = u.s4;
            }
            psum += __shfl_xor(psum, 16);
            psum += __shfl_xor(psum, 32);
            l[qa] += psum;
        }

        // ---- O^T += V^T * P^T : 2 kv-chunks x 8 d-tiles (f16)
        #pragma unroll
        for (int c = 0; c < 2; ++c) {
            half8 pf0 = *(const half8*)&P_w[(r16 * 64 + 32 * c + 8 * g) ^ pswz];
            half8 pf1 = *(const half8*)&P_w[(1024 + r16 * 64 + 32 * c + 8 * g) ^ pswz];
            #pragma unroll
            for (int dt = 0; dt < 8; ++dt) {
                int row = 16 * dt + r16;
                half8 vf = *(const half8*)&vb[(row * 64 + 32 * c + 8 * g) ^ ((row & 7) << 3)];
                o[0][dt] = __builtin_amdgcn_mfma_f32_16x16x32_f16(vf, pf0, o[0][dt], 0, 0, 0);
                o[1][dt] = __builtin_amdgcn_mfma_f32_16x16x32_f16(vf, pf1, o[1][dt], 0, 0, 0);
            }
        }

        if (it + 1 < t1) WRITET(buf ^ 1);
        __syncthreads();
        buf ^= 1;
    }

    // ---- epilogue: partial O (pre-division, f16) + (m[log2], l)
    #pragma unroll
    for (int qa = 0; qa < 2; ++qa) {
        ushort* obase = Opb + ((size_t)sp * N_TOK + qbase + 16 * qa + r16) * D + 4 * g;
        #pragma unroll
        for (int dt = 0; dt < 8; ++dt) {
            half4 pk;
            #pragma unroll
            for (int r = 0; r < 4; ++r) pk[r] = (_Float16)o[qa][dt][r];
            *(half4*)(obase + 16 * dt) = pk;
        }
        if (g == 0) {
            int qt = (qbase + 16 * qa) >> 4;
            float* ml = ML + ((size_t)sp * QTILES + qt) * 32;
            ml[r16] = m[qa];
            ml[16 + r16] = l[qa];
        }
    }
}

// -------- kernel 3: merge the NS KV-split partials (16B loads, 8 elem/thr) --
template<int NS>
__global__ void merge_kernel(const ushort* __restrict__ Opb, const float* __restrict__ ML,
                             float* __restrict__ out) {
    int i = blockIdx.x * blockDim.x + threadIdx.x;
    int e = i * 8;
    if (e >= N_TOK * D) return;
    int q = e >> 7;
    int qt = q >> 4, qr = q & 15;
    float mv[NS], lv[NS];
    float M = -INFINITY;
    #pragma unroll
    for (int s = 0; s < NS; ++s) {
        const float* ml = ML + ((size_t)s * QTILES + qt) * 32;
        mv[s] = ml[qr];
        lv[s] = ml[16 + qr];
        M = fmaxf(M, mv[s]);
    }
    float L = 0.f, a[NS];
    #pragma unroll
    for (int s = 0; s < NS; ++s) { a[s] = __builtin_amdgcn_exp2f(mv[s] - M); L += a[s] * lv[s]; }
    float inv = 1.f / L;
    float acc[8];
    #pragma unroll
    for (int r = 0; r < 8; ++r) acc[r] = 0.f;
    #pragma unroll
    for (int s = 0; s < NS; ++s) {
        half8 ov = *(const half8*)(Opb + (size_t)s * N_TOK * D + e);
        #pragma unroll
        for (int r = 0; r < 8; ++r) acc[r] += (float)ov[r] * a[s];
    }
    f32x4 o0, o1;
    #pragma unroll
    for (int r = 0; r < 4; ++r) { o0[r] = acc[r] * inv; o1[r] = acc[4 + r] * inv; }
    *(f32x4*)(out + e) = o0;
    *(f32x4*)(out + e + 4) = o1;
}

extern "C" void kernel_launch(void* const* d_in, const int* in_sizes, int n_in,
                              void* d_out, int out_size, void* d_ws, size_t ws_size,
                              hipStream_t stream) {
    const float* X  = (const float*)d_in[0];
    const float* Wq = (const float*)d_in[1];
    const float* Wk = (const float*)d_in[2];
    const float* Wv = (const float*)d_in[3];
    float* out = (float*)d_out;

    char* ws = (char*)d_ws;
    ushort* Qh  = (ushort*)(ws);                   // 2 MB (f16, pre-scaled log2e)
    ushort* Kh  = (ushort*)(ws + 2097152);         // 2 MB (f16)
    ushort* Vt  = (ushort*)(ws + 4194304);         // 2 MB (f16, transposed)
    ushort* Opb = (ushort*)(ws + 6291456);         // NS * 2 MB (f16 partials)

    const size_t op_off = 6291456;
    const size_t need8 = op_off + (size_t)8 * N_TOK * D * 2 + (size_t)8 * QTILES * 32 * 4;

    proj_kernel<<<256, 256, 0, stream>>>(X, Wq, Wk, Wv, Qh, Kh, Vt);

    if (ws_size >= need8) {
        float* ML = (float*)(ws + op_off + (size_t)8 * N_TOK * D * 2);
        flash_kernel<8><<<(N_TOK / 128) * 8, 256, 0, stream>>>(Qh, Kh, Vt, Opb, ML);
        merge_kernel<8><<<(N_TOK * D / 8 + 255) / 256, 256, 0, stream>>>(Opb, ML, out);
    } else {
        float* ML = (float*)(ws + op_off + (size_t)4 * N_TOK * D * 2);
        flash_kernel<4><<<(N_TOK / 128) * 4, 256, 0, stream>>>(Qh, Kh, Vt, Opb, ML);
        merge_kernel<4><<<(N_TOK * D / 8 + 255) / 256, 256, 0, stream>>>(Opb, ML, out);
    }
}

// Round 22
// 70.604 us; speedup vs baseline: 1.0809x; 1.0230x over previous
//
#include <hip/hip_runtime.h>
#include <hip/hip_bf16.h>
#include <stdint.h>

#define N_TOK 8192
#define D 128
#define QTILES (N_TOK / 16)    // 512
#define KVB 64                 // kv rows per staged tile
#define KVTILES (N_TOK / KVB)  // 128
#define LOG2E 1.4426950408889634f

typedef __attribute__((ext_vector_type(8))) short short8;      // 8x16b frag
typedef __attribute__((ext_vector_type(4))) short short4v;     // 4x16b (8B)
typedef __attribute__((ext_vector_type(4))) float f32x4;       // MFMA accum
typedef __attribute__((ext_vector_type(8))) _Float16 half8;    // f16x8 frag
typedef __attribute__((ext_vector_type(4))) _Float16 half4;    // 4 f16 (8B)
typedef __attribute__((ext_vector_type(2))) __fp16 fp16x2;     // cvt_pkrtz ret

__device__ __forceinline__ f32x4 zero4() {
    f32x4 z; z[0] = 0.f; z[1] = 0.f; z[2] = 0.f; z[3] = 0.f; return z;
}
__device__ __forceinline__ float ex2(float x) {
    return __builtin_amdgcn_exp2f(x);   // raw v_exp_f32 (2^x), no libm wrapper
}
__device__ __forceinline__ float max16(const f32x4* s) {
    // 16-value max via v_max3 fusion (nested triples)
    float a = fmaxf(fmaxf(s[0][0], s[0][1]), s[0][2]);
    float b = fmaxf(fmaxf(s[0][3], s[1][0]), s[1][1]);
    float c = fmaxf(fmaxf(s[1][2], s[1][3]), s[2][0]);
    float d = fmaxf(fmaxf(s[2][1], s[2][2]), s[2][3]);
    float e = fmaxf(fmaxf(s[3][0], s[3][1]), s[3][2]);
    return fmaxf(fmaxf(fmaxf(a, b), c), fmaxf(fmaxf(d, e), s[3][3]));
}
// load 8 consecutive f32 and convert to f16x8 fragment (RTN)
__device__ __forceinline__ half8 ld_f32_as_h8(const float* p) {
    f32x4 a = *(const f32x4*)(p);
    f32x4 b = *(const f32x4*)(p + 4);
    half8 w;
    #pragma unroll
    for (int j = 0; j < 4; ++j) {
        w[j] = (_Float16)a[j];
        w[4 + j] = (_Float16)b[j];
    }
    return w;
}

// -------- kernel 1: projections, single f16 MFMA, W converted in-register ---
// (R21-proven) 256 blocks x 4 waves; wave w handles jt in {2w, 2w+1}.
// Q pre-scaled by log2(e) so flash softmax runs in exp2 domain.
__global__ __launch_bounds__(256) void proj_kernel(
    const float* __restrict__ X, const float* __restrict__ Wq,
    const float* __restrict__ Wk, const float* __restrict__ Wv,
    ushort* __restrict__ Qh, ushort* __restrict__ Kh, ushort* __restrict__ Vt) {
    const int tid = threadIdx.x;
    const int lane = tid & 63;
    const int wid = tid >> 6;
    const int g = lane >> 4, r16 = lane & 15;
    const int qbase = blockIdx.x * 32;

    half8 xf[2][4];
    #pragma unroll
    for (int qa = 0; qa < 2; ++qa) {
        const float* xr = X + (size_t)(qbase + 16 * qa + r16) * D + 8 * g;
        #pragma unroll
        for (int ds = 0; ds < 4; ++ds)
            xf[qa][ds] = ld_f32_as_h8(xr + 32 * ds);
    }

    #pragma unroll
    for (int m = 0; m < 2; ++m) {
        const float* W = m ? Wk : Wq;
        ushort* O = m ? Kh : Qh;
        const float sc = m ? 1.0f : LOG2E;
        #pragma unroll
        for (int jj = 0; jj < 2; ++jj) {
            int jt = 2 * wid + jj;
            const float* wr = W + (size_t)(16 * jt + r16) * D + 8 * g;
            f32x4 acc[2] = {zero4(), zero4()};
            #pragma unroll
            for (int ds = 0; ds < 4; ++ds) {
                half8 wf = ld_f32_as_h8(wr + 32 * ds);
                #pragma unroll
                for (int qa = 0; qa < 2; ++qa)
                    acc[qa] = __builtin_amdgcn_mfma_f32_16x16x32_f16(wf, xf[qa][ds], acc[qa], 0, 0, 0);
            }
            #pragma unroll
            for (int qa = 0; qa < 2; ++qa) {
                half4 pk;
                #pragma unroll
                for (int r = 0; r < 4; ++r) pk[r] = (_Float16)(acc[qa][r] * sc);
                *(half4*)(O + (size_t)(qbase + 16 * qa + r16) * D + 16 * jt + 4 * g) = pk;
            }
        }
    }
    {
        #pragma unroll
        for (int jj = 0; jj < 2; ++jj) {
            int jt = 2 * wid + jj;
            const float* wr = Wv + (size_t)(16 * jt + r16) * D + 8 * g;
            f32x4 acc[2] = {zero4(), zero4()};
            #pragma unroll
            for (int ds = 0; ds < 4; ++ds) {
                half8 wf = ld_f32_as_h8(wr + 32 * ds);
                #pragma unroll
                for (int qa = 0; qa < 2; ++qa)
                    acc[qa] = __builtin_amdgcn_mfma_f32_16x16x32_f16(xf[qa][ds], wf, acc[qa], 0, 0, 0);
            }
            #pragma unroll
            for (int qa = 0; qa < 2; ++qa) {
                half4 pk;
                #pragma unroll
                for (int r = 0; r < 4; ++r) pk[r] = (_Float16)acc[qa][r];
                *(half4*)(Vt + (size_t)(16 * jt + r16) * N_TOK + qbase + 16 * qa + 4 * g) = pk;
            }
        }
    }
}

// -------- kernel 2: flash attention, double-buffered K+V LDS (R17-proven) ---
// setprio RESTORED (R21 A/B: removal cost +1.7us; attn softmax gives waves
// phase diversity -> setprio around MFMA clusters helps, m191-case).
// 4 waves/block, 32 q-rows each. NS=8 -> sp == XCD id (L2-affine K/V).
// Softmax in exp2 domain via raw v_exp_f32; m[] holds log2-units max.
template<int NS>
__global__ __launch_bounds__(256, 2) void flash_kernel(
    const ushort* __restrict__ Qh, const ushort* __restrict__ Kh,
    const ushort* __restrict__ Vt, ushort* __restrict__ Opb, float* __restrict__ ML) {
    __shared__ __align__(16) ushort K_lds[2][KVB * D];   // 2 x 16 KB f16
    __shared__ __align__(16) ushort V_lds[2][D * KVB];   // 2 x 16 KB f16
    __shared__ __align__(16) ushort P_lds[4 * 2048];     // 16 KB f16

    const int tid = threadIdx.x;
    const int lane = tid & 63;
    const int wid = tid >> 6;
    const int g = lane >> 4, r16 = lane & 15;
    const int sp = blockIdx.x % NS;        // == XCD id when NS==8
    const int qg = blockIdx.x / NS;
    const int t0 = (KVTILES * sp) / NS;
    const int t1 = (KVTILES * (sp + 1)) / NS;
    const int qbase = qg * 128 + wid * 32;
    const int pswz = (r16 & 7) << 3;

    half8 qf[2][4];
    #pragma unroll
    for (int qa = 0; qa < 2; ++qa) {
        const ushort* qr = Qh + (size_t)(qbase + 16 * qa + r16) * D + 8 * g;
        #pragma unroll
        for (int ds = 0; ds < 4; ++ds)
            qf[qa][ds] = *(const half8*)(qr + 32 * ds);
    }

    float m[2] = {-INFINITY, -INFINITY}, l[2] = {0.f, 0.f};
    f32x4 o[2][8];
    #pragma unroll
    for (int qa = 0; qa < 2; ++qa)
        #pragma unroll
        for (int dt = 0; dt < 8; ++dt) o[qa][dt] = zero4();

    ushort* P_w = &P_lds[wid * 2048];

    short8 sk[4], sv[4];

    auto LOADT = [&](int it) {
        const int kv = it * KVB;
        #pragma unroll
        for (int rr = 0; rr < 4; ++rr) {
            int idx = tid + 256 * rr;              // [0,1024)
            int row = idx >> 4, seg = idx & 15;
            sk[rr] = *(const short8*)(Kh + (size_t)(kv + row) * D + seg * 8);
        }
        #pragma unroll
        for (int rr = 0; rr < 4; ++rr) {
            int idx = tid + 256 * rr;              // [0,1024)
            int row = idx >> 3, seg = idx & 7;
            sv[rr] = *(const short8*)(Vt + (size_t)row * N_TOK + kv + seg * 8);
        }
    };
    auto WRITET = [&](int b) {
        #pragma unroll
        for (int rr = 0; rr < 4; ++rr) {
            int idx = tid + 256 * rr;
            int row = idx >> 4, seg = idx & 15;
            *(short8*)&K_lds[b][(row * 128 + seg * 8) ^ ((row & 7) << 3)] = sk[rr];
        }
        #pragma unroll
        for (int rr = 0; rr < 4; ++rr) {
            int idx = tid + 256 * rr;
            int row = idx >> 3, seg = idx & 7;
            *(short8*)&V_lds[b][(row * 64 + seg * 8) ^ ((row & 7) << 3)] = sv[rr];
        }
    };

    LOADT(t0);
    WRITET(0);
    __syncthreads();

    int buf = 0;
    for (int it = t0; it < t1; ++it) {
        if (it + 1 < t1) LOADT(it + 1);

        const ushort* kb = K_lds[buf];
        const ushort* vb = V_lds[buf];

        // ---- S^T = K*Q^T (scores in log2 domain via Q pre-scaling)
        f32x4 s[2][4];
        #pragma unroll
        for (int qa = 0; qa < 2; ++qa)
            #pragma unroll
            for (int t = 0; t < 4; ++t) s[qa][t] = zero4();
        __builtin_amdgcn_s_setprio(1);
        #pragma unroll
        for (int t = 0; t < 4; ++t) {
            #pragma unroll
            for (int ds = 0; ds < 4; ++ds) {
                int row = 16 * t + r16;
                half8 kf = *(const half8*)&kb[(row * 128 + 32 * ds + 8 * g) ^ ((row & 7) << 3)];
                #pragma unroll
                for (int qa = 0; qa < 2; ++qa)
                    s[qa][t] = __builtin_amdgcn_mfma_f32_16x16x32_f16(kf, qf[qa][ds], s[qa][t], 0, 0, 0);
            }
        }
        __builtin_amdgcn_s_setprio(0);

        // ---- online softmax (exp2 domain, lane-local per r16)
        #pragma unroll
        for (int qa = 0; qa < 2; ++qa) {
            float tm = max16(s[qa]);
            tm = fmaxf(tm, __shfl_xor(tm, 16));
            tm = fmaxf(tm, __shfl_xor(tm, 32));
            // exact-skip rescale: when no lane's max grew, scale==1 for all
            if (!__all(tm <= m[qa])) {
                float mnew = fmaxf(m[qa], tm);
                float scale = ex2(m[qa] - mnew);
                l[qa] *= scale;
                #pragma unroll
                for (int dt = 0; dt < 8; ++dt) o[qa][dt] *= scale;
                m[qa] = mnew;
            }
            float psum = 0.f;
            #pragma unroll
            for (int t = 0; t < 4; ++t) {
                float p0 = ex2(s[qa][t][0] - m[qa]);
                float p1 = ex2(s[qa][t][1] - m[qa]);
                float p2 = ex2(s[qa][t][2] - m[qa]);
                float p3 = ex2(s[qa][t][3] - m[qa]);
                psum += (p0 + p1) + (p2 + p3);
                union { fp16x2 h[2]; short4v s4; } u;
                u.h[0] = __builtin_amdgcn_cvt_pkrtz(p0, p1);
                u.h[1] = __builtin_amdgcn_cvt_pkrtz(p2, p3);
                *(short4v*)&P_w[(qa * 1024 + r16 * 64 + 16 * t + 4 * g) ^ pswz] = u.s4;
            }
            psum += __shfl_xor(psum, 16);
            psum += __shfl_xor(psum, 32);
            l[qa] += psum;
        }

        // ---- O^T += V^T * P^T : 2 kv-chunks x 8 d-tiles (f16)
        __builtin_amdgcn_s_setprio(1);
        #pragma unroll
        for (int c = 0; c < 2; ++c) {
            half8 pf0 = *(const half8*)&P_w[(r16 * 64 + 32 * c + 8 * g) ^ pswz];
            half8 pf1 = *(const half8*)&P_w[(1024 + r16 * 64 + 32 * c + 8 * g) ^ pswz];
            #pragma unroll
            for (int dt = 0; dt < 8; ++dt) {
                int row = 16 * dt + r16;
                half8 vf = *(const half8*)&vb[(row * 64 + 32 * c + 8 * g) ^ ((row & 7) << 3)];
                o[0][dt] = __builtin_amdgcn_mfma_f32_16x16x32_f16(vf, pf0, o[0][dt], 0, 0, 0);
                o[1][dt] = __builtin_amdgcn_mfma_f32_16x16x32_f16(vf, pf1, o[1][dt], 0, 0, 0);
            }
        }
        __builtin_amdgcn_s_setprio(0);

        if (it + 1 < t1) WRITET(buf ^ 1);
        __syncthreads();
        buf ^= 1;
    }

    // ---- epilogue: partial O (pre-division, f16) + (m[log2], l)
    #pragma unroll
    for (int qa = 0; qa < 2; ++qa) {
        ushort* obase = Opb + ((size_t)sp * N_TOK + qbase + 16 * qa + r16) * D + 4 * g;
        #pragma unroll
        for (int dt = 0; dt < 8; ++dt) {
            half4 pk;
            #pragma unroll
            for (int r = 0; r < 4; ++r) pk[r] = (_Float16)o[qa][dt][r];
            *(half4*)(obase + 16 * dt) = pk;
        }
        if (g == 0) {
            int qt = (qbase + 16 * qa) >> 4;
            float* ml = ML + ((size_t)sp * QTILES + qt) * 32;
            ml[r16] = m[qa];
            ml[16 + r16] = l[qa];
        }
    }
}

// -------- kernel 3: merge the NS KV-split partials (16B loads, 8 elem/thr) --
template<int NS>
__global__ void merge_kernel(const ushort* __restrict__ Opb, const float* __restrict__ ML,
                             float* __restrict__ out) {
    int i = blockIdx.x * blockDim.x + threadIdx.x;
    int e = i * 8;
    if (e >= N_TOK * D) return;
    int q = e >> 7;
    int qt = q >> 4, qr = q & 15;
    float mv[NS], lv[NS];
    float M = -INFINITY;
    #pragma unroll
    for (int s = 0; s < NS; ++s) {
        const float* ml = ML + ((size_t)s * QTILES + qt) * 32;
        mv[s] = ml[qr];
        lv[s] = ml[16 + qr];
        M = fmaxf(M, mv[s]);
    }
    float L = 0.f, a[NS];
    #pragma unroll
    for (int s = 0; s < NS; ++s) { a[s] = __builtin_amdgcn_exp2f(mv[s] - M); L += a[s] * lv[s]; }
    float inv = 1.f / L;
    float acc[8];
    #pragma unroll
    for (int r = 0; r < 8; ++r) acc[r] = 0.f;
    #pragma unroll
    for (int s = 0; s < NS; ++s) {
        half8 ov = *(const half8*)(Opb + (size_t)s * N_TOK * D + e);
        #pragma unroll
        for (int r = 0; r < 8; ++r) acc[r] += (float)ov[r] * a[s];
    }
    f32x4 o0, o1;
    #pragma unroll
    for (int r = 0; r < 4; ++r) { o0[r] = acc[r] * inv; o1[r] = acc[4 + r] * inv; }
    *(f32x4*)(out + e) = o0;
    *(f32x4*)(out + e + 4) = o1;
}

extern "C" void kernel_launch(void* const* d_in, const int* in_sizes, int n_in,
                              void* d_out, int out_size, void* d_ws, size_t ws_size,
                              hipStream_t stream) {
    const float* X  = (const float*)d_in[0];
    const float* Wq = (const float*)d_in[1];
    const float* Wk = (const float*)d_in[2];
    const float* Wv = (const float*)d_in[3];
    float* out = (float*)d_out;

    char* ws = (char*)d_ws;
    ushort* Qh  = (ushort*)(ws);                   // 2 MB (f16, pre-scaled log2e)
    ushort* Kh  = (ushort*)(ws + 2097152);         // 2 MB (f16)
    ushort* Vt  = (ushort*)(ws + 4194304);         // 2 MB (f16, transposed)
    ushort* Opb = (ushort*)(ws + 6291456);         // NS * 2 MB (f16 partials)

    const size_t op_off = 6291456;
    const size_t need8 = op_off + (size_t)8 * N_TOK * D * 2 + (size_t)8 * QTILES * 32 * 4;

    proj_kernel<<<256, 256, 0, stream>>>(X, Wq, Wk, Wv, Qh, Kh, Vt);

    if (ws_size >= need8) {
        float* ML = (float*)(ws + op_off + (size_t)8 * N_TOK * D * 2);
        flash_kernel<8><<<(N_TOK / 128) * 8, 256, 0, stream>>>(Qh, Kh, Vt, Opb, ML);
        merge_kernel<8><<<(N_TOK * D / 8 + 255) / 256, 256, 0, stream>>>(Opb, ML, out);
    } else {
        float* ML = (float*)(ws + op_off + (size_t)4 * N_TOK * D * 2);
        flash_kernel<4><<<(N_TOK / 128) * 4, 256, 0, stream>>>(Qh, Kh, Vt, Opb, ML);
        merge_kernel<4><<<(N_TOK * D / 8 + 255) / 256, 256, 0, stream>>>(Opb, ML, out);
    }
}

// Round 23
// 68.803 us; speedup vs baseline: 1.1092x; 1.0262x over previous
//
#include <hip/hip_runtime.h>
#include <hip/hip_bf16.h>
#include <stdint.h>

#define N_TOK 8192
#define D 128
#define QTILES (N_TOK / 16)    // 512
#define KVB 64                 // kv rows per staged tile
#define KVTILES (N_TOK / KVB)  // 128
#define LOG2E 1.4426950408889634f

typedef __attribute__((ext_vector_type(8))) short short8;      // 8x16b frag
typedef __attribute__((ext_vector_type(4))) short short4v;     // 4x16b (8B)
typedef __attribute__((ext_vector_type(4))) float f32x4;       // MFMA accum
typedef __attribute__((ext_vector_type(8))) _Float16 half8;    // f16x8 frag
typedef __attribute__((ext_vector_type(4))) _Float16 half4;    // 4 f16 (8B)
typedef __attribute__((ext_vector_type(2))) __fp16 fp16x2;     // cvt_pkrtz ret
typedef __attribute__((ext_vector_type(2))) unsigned int uint2v;

__device__ __forceinline__ f32x4 zero4() {
    f32x4 z; z[0] = 0.f; z[1] = 0.f; z[2] = 0.f; z[3] = 0.f; return z;
}
__device__ __forceinline__ float ex2(float x) {
    return __builtin_amdgcn_exp2f(x);   // raw v_exp_f32 (2^x), no libm wrapper
}
__device__ __forceinline__ float max16(const f32x4* s) {
    // 16-value max via v_max3 fusion (nested triples)
    float a = fmaxf(fmaxf(s[0][0], s[0][1]), s[0][2]);
    float b = fmaxf(fmaxf(s[0][3], s[1][0]), s[1][1]);
    float c = fmaxf(fmaxf(s[1][2], s[1][3]), s[2][0]);
    float d = fmaxf(fmaxf(s[2][1], s[2][2]), s[2][3]);
    float e = fmaxf(fmaxf(s[3][0], s[3][1]), s[3][2]);
    return fmaxf(fmaxf(fmaxf(a, b), c), fmaxf(fmaxf(d, e), s[3][3]));
}

// ---- cross-lane 4-group reductions (lanes l, l^16, l^32, l^48) -------------
// gfx950 permlane{16,32}_swap are VALU (~4cy) vs shfl_xor's ds_swizzle
// (LDS pipe, ~60-120cy latency, on softmax's critical path).
// swap(x,x) yields {own, partner} across the two results in every lane, so
// fmax/add of the pair == the xor-stage, bit-identical (commutative ops).
#if __has_builtin(__builtin_amdgcn_permlane16_swap) && __has_builtin(__builtin_amdgcn_permlane32_swap)
__device__ __forceinline__ float red16_max(float x) {
    union { float f; unsigned u; } c; c.f = x;
    uint2v r = __builtin_amdgcn_permlane16_swap(c.u, c.u, false, false);
    union { unsigned u; float f; } a, b; a.u = r[0]; b.u = r[1];
    return fmaxf(a.f, b.f);
}
__device__ __forceinline__ float red32_max(float x) {
    union { float f; unsigned u; } c; c.f = x;
    uint2v r = __builtin_amdgcn_permlane32_swap(c.u, c.u, false, false);
    union { unsigned u; float f; } a, b; a.u = r[0]; b.u = r[1];
    return fmaxf(a.f, b.f);
}
__device__ __forceinline__ float red16_sum(float x) {
    union { float f; unsigned u; } c; c.f = x;
    uint2v r = __builtin_amdgcn_permlane16_swap(c.u, c.u, false, false);
    union { unsigned u; float f; } a, b; a.u = r[0]; b.u = r[1];
    return a.f + b.f;
}
__device__ __forceinline__ float red32_sum(float x) {
    union { float f; unsigned u; } c; c.f = x;
    uint2v r = __builtin_amdgcn_permlane32_swap(c.u, c.u, false, false);
    union { unsigned u; float f; } a, b; a.u = r[0]; b.u = r[1];
    return a.f + b.f;
}
#else
__device__ __forceinline__ float red16_max(float x) { return fmaxf(x, __shfl_xor(x, 16)); }
__device__ __forceinline__ float red32_max(float x) { return fmaxf(x, __shfl_xor(x, 32)); }
__device__ __forceinline__ float red16_sum(float x) { return x + __shfl_xor(x, 16); }
__device__ __forceinline__ float red32_sum(float x) { return x + __shfl_xor(x, 32); }
#endif

// load 8 consecutive f32 and convert to f16x8 fragment (RTN)
__device__ __forceinline__ half8 ld_f32_as_h8(const float* p) {
    f32x4 a = *(const f32x4*)(p);
    f32x4 b = *(const f32x4*)(p + 4);
    half8 w;
    #pragma unroll
    for (int j = 0; j < 4; ++j) {
        w[j] = (_Float16)a[j];
        w[4 + j] = (_Float16)b[j];
    }
    return w;
}

// -------- kernel 1: projections, single f16 MFMA, W converted in-register ---
// (R21-proven) 256 blocks x 4 waves; wave w handles jt in {2w, 2w+1}.
// Q pre-scaled by log2(e) so flash softmax runs in exp2 domain.
__global__ __launch_bounds__(256) void proj_kernel(
    const float* __restrict__ X, const float* __restrict__ Wq,
    const float* __restrict__ Wk, const float* __restrict__ Wv,
    ushort* __restrict__ Qh, ushort* __restrict__ Kh, ushort* __restrict__ Vt) {
    const int tid = threadIdx.x;
    const int lane = tid & 63;
    const int wid = tid >> 6;
    const int g = lane >> 4, r16 = lane & 15;
    const int qbase = blockIdx.x * 32;

    half8 xf[2][4];
    #pragma unroll
    for (int qa = 0; qa < 2; ++qa) {
        const float* xr = X + (size_t)(qbase + 16 * qa + r16) * D + 8 * g;
        #pragma unroll
        for (int ds = 0; ds < 4; ++ds)
            xf[qa][ds] = ld_f32_as_h8(xr + 32 * ds);
    }

    #pragma unroll
    for (int m = 0; m < 2; ++m) {
        const float* W = m ? Wk : Wq;
        ushort* O = m ? Kh : Qh;
        const float sc = m ? 1.0f : LOG2E;
        #pragma unroll
        for (int jj = 0; jj < 2; ++jj) {
            int jt = 2 * wid + jj;
            const float* wr = W + (size_t)(16 * jt + r16) * D + 8 * g;
            f32x4 acc[2] = {zero4(), zero4()};
            #pragma unroll
            for (int ds = 0; ds < 4; ++ds) {
                half8 wf = ld_f32_as_h8(wr + 32 * ds);
                #pragma unroll
                for (int qa = 0; qa < 2; ++qa)
                    acc[qa] = __builtin_amdgcn_mfma_f32_16x16x32_f16(wf, xf[qa][ds], acc[qa], 0, 0, 0);
            }
            #pragma unroll
            for (int qa = 0; qa < 2; ++qa) {
                half4 pk;
                #pragma unroll
                for (int r = 0; r < 4; ++r) pk[r] = (_Float16)(acc[qa][r] * sc);
                *(half4*)(O + (size_t)(qbase + 16 * qa + r16) * D + 16 * jt + 4 * g) = pk;
            }
        }
    }
    {
        #pragma unroll
        for (int jj = 0; jj < 2; ++jj) {
            int jt = 2 * wid + jj;
            const float* wr = Wv + (size_t)(16 * jt + r16) * D + 8 * g;
            f32x4 acc[2] = {zero4(), zero4()};
            #pragma unroll
            for (int ds = 0; ds < 4; ++ds) {
                half8 wf = ld_f32_as_h8(wr + 32 * ds);
                #pragma unroll
                for (int qa = 0; qa < 2; ++qa)
                    acc[qa] = __builtin_amdgcn_mfma_f32_16x16x32_f16(xf[qa][ds], wf, acc[qa], 0, 0, 0);
            }
            #pragma unroll
            for (int qa = 0; qa < 2; ++qa) {
                half4 pk;
                #pragma unroll
                for (int r = 0; r < 4; ++r) pk[r] = (_Float16)acc[qa][r];
                *(half4*)(Vt + (size_t)(16 * jt + r16) * N_TOK + qbase + 16 * qa + 4 * g) = pk;
            }
        }
    }
}

// -------- kernel 2: flash attention, double-buffered K+V LDS (R22-proven) ---
// setprio kept (R21 A/B: removal cost +1.7us). Softmax cross-lane reductions
// now via permlane{16,32}_swap (VALU) instead of ds_swizzle (LDS latency).
// 4 waves/block, 32 q-rows each. NS=8 -> sp == XCD id (L2-affine K/V).
template<int NS>
__global__ __launch_bounds__(256, 2) void flash_kernel(
    const ushort* __restrict__ Qh, const ushort* __restrict__ Kh,
    const ushort* __restrict__ Vt, ushort* __restrict__ Opb, float* __restrict__ ML) {
    __shared__ __align__(16) ushort K_lds[2][KVB * D];   // 2 x 16 KB f16
    __shared__ __align__(16) ushort V_lds[2][D * KVB];   // 2 x 16 KB f16
    __shared__ __align__(16) ushort P_lds[4 * 2048];     // 16 KB f16

    const int tid = threadIdx.x;
    const int lane = tid & 63;
    const int wid = tid >> 6;
    const int g = lane >> 4, r16 = lane & 15;
    const int sp = blockIdx.x % NS;        // == XCD id when NS==8
    const int qg = blockIdx.x / NS;
    const int t0 = (KVTILES * sp) / NS;
    const int t1 = (KVTILES * (sp + 1)) / NS;
    const int qbase = qg * 128 + wid * 32;
    const int pswz = (r16 & 7) << 3;

    half8 qf[2][4];
    #pragma unroll
    for (int qa = 0; qa < 2; ++qa) {
        const ushort* qr = Qh + (size_t)(qbase + 16 * qa + r16) * D + 8 * g;
        #pragma unroll
        for (int ds = 0; ds < 4; ++ds)
            qf[qa][ds] = *(const half8*)(qr + 32 * ds);
    }

    float m[2] = {-INFINITY, -INFINITY}, l[2] = {0.f, 0.f};
    f32x4 o[2][8];
    #pragma unroll
    for (int qa = 0; qa < 2; ++qa)
        #pragma unroll
        for (int dt = 0; dt < 8; ++dt) o[qa][dt] = zero4();

    ushort* P_w = &P_lds[wid * 2048];

    short8 sk[4], sv[4];

    auto LOADT = [&](int it) {
        const int kv = it * KVB;
        #pragma unroll
        for (int rr = 0; rr < 4; ++rr) {
            int idx = tid + 256 * rr;              // [0,1024)
            int row = idx >> 4, seg = idx & 15;
            sk[rr] = *(const short8*)(Kh + (size_t)(kv + row) * D + seg * 8);
        }
        #pragma unroll
        for (int rr = 0; rr < 4; ++rr) {
            int idx = tid + 256 * rr;              // [0,1024)
            int row = idx >> 3, seg = idx & 7;
            sv[rr] = *(const short8*)(Vt + (size_t)row * N_TOK + kv + seg * 8);
        }
    };
    auto WRITET = [&](int b) {
        #pragma unroll
        for (int rr = 0; rr < 4; ++rr) {
            int idx = tid + 256 * rr;
            int row = idx >> 4, seg = idx & 15;
            *(short8*)&K_lds[b][(row * 128 + seg * 8) ^ ((row & 7) << 3)] = sk[rr];
        }
        #pragma unroll
        for (int rr = 0; rr < 4; ++rr) {
            int idx = tid + 256 * rr;
            int row = idx >> 3, seg = idx & 7;
            *(short8*)&V_lds[b][(row * 64 + seg * 8) ^ ((row & 7) << 3)] = sv[rr];
        }
    };

    LOADT(t0);
    WRITET(0);
    __syncthreads();

    int buf = 0;
    for (int it = t0; it < t1; ++it) {
        if (it + 1 < t1) LOADT(it + 1);

        const ushort* kb = K_lds[buf];
        const ushort* vb = V_lds[buf];

        // ---- S^T = K*Q^T (scores in log2 domain via Q pre-scaling)
        f32x4 s[2][4];
        #pragma unroll
        for (int qa = 0; qa < 2; ++qa)
            #pragma unroll
            for (int t = 0; t < 4; ++t) s[qa][t] = zero4();
        __builtin_amdgcn_s_setprio(1);
        #pragma unroll
        for (int t = 0; t < 4; ++t) {
            #pragma unroll
            for (int ds = 0; ds < 4; ++ds) {
                int row = 16 * t + r16;
                half8 kf = *(const half8*)&kb[(row * 128 + 32 * ds + 8 * g) ^ ((row & 7) << 3)];
                #pragma unroll
                for (int qa = 0; qa < 2; ++qa)
                    s[qa][t] = __builtin_amdgcn_mfma_f32_16x16x32_f16(kf, qf[qa][ds], s[qa][t], 0, 0, 0);
            }
        }
        __builtin_amdgcn_s_setprio(0);

        // ---- online softmax (exp2 domain, lane-local per r16)
        #pragma unroll
        for (int qa = 0; qa < 2; ++qa) {
            float tm = max16(s[qa]);
            tm = red16_max(tm);
            tm = red32_max(tm);
            // exact-skip rescale: when no lane's max grew, scale==1 for all
            if (!__all(tm <= m[qa])) {
                float mnew = fmaxf(m[qa], tm);
                float scale = ex2(m[qa] - mnew);
                l[qa] *= scale;
                #pragma unroll
                for (int dt = 0; dt < 8; ++dt) o[qa][dt] *= scale;
                m[qa] = mnew;
            }
            float psum = 0.f;
            #pragma unroll
            for (int t = 0; t < 4; ++t) {
                float p0 = ex2(s[qa][t][0] - m[qa]);
                float p1 = ex2(s[qa][t][1] - m[qa]);
                float p2 = ex2(s[qa][t][2] - m[qa]);
                float p3 = ex2(s[qa][t][3] - m[qa]);
                psum += (p0 + p1) + (p2 + p3);
                union { fp16x2 h[2]; short4v s4; } u;
                u.h[0] = __builtin_amdgcn_cvt_pkrtz(p0, p1);
                u.h[1] = __builtin_amdgcn_cvt_pkrtz(p2, p3);
                *(short4v*)&P_w[(qa * 1024 + r16 * 64 + 16 * t + 4 * g) ^ pswz] = u.s4;
            }
            psum = red16_sum(psum);
            psum = red32_sum(psum);
            l[qa] += psum;
        }

        // ---- O^T += V^T * P^T : 2 kv-chunks x 8 d-tiles (f16)
        __builtin_amdgcn_s_setprio(1);
        #pragma unroll
        for (int c = 0; c < 2; ++c) {
            half8 pf0 = *(const half8*)&P_w[(r16 * 64 + 32 * c + 8 * g) ^ pswz];
            half8 pf1 = *(const half8*)&P_w[(1024 + r16 * 64 + 32 * c + 8 * g) ^ pswz];
            #pragma unroll
            for (int dt = 0; dt < 8; ++dt) {
                int row = 16 * dt + r16;
                half8 vf = *(const half8*)&vb[(row * 64 + 32 * c + 8 * g) ^ ((row & 7) << 3)];
                o[0][dt] = __builtin_amdgcn_mfma_f32_16x16x32_f16(vf, pf0, o[0][dt], 0, 0, 0);
                o[1][dt] = __builtin_amdgcn_mfma_f32_16x16x32_f16(vf, pf1, o[1][dt], 0, 0, 0);
            }
        }
        __builtin_amdgcn_s_setprio(0);

        if (it + 1 < t1) WRITET(buf ^ 1);
        __syncthreads();
        buf ^= 1;
    }

    // ---- epilogue: partial O (pre-division, f16) + (m[log2], l)
    #pragma unroll
    for (int qa = 0; qa < 2; ++qa) {
        ushort* obase = Opb + ((size_t)sp * N_TOK + qbase + 16 * qa + r16) * D + 4 * g;
        #pragma unroll
        for (int dt = 0; dt < 8; ++dt) {
            half4 pk;
            #pragma unroll
            for (int r = 0; r < 4; ++r) pk[r] = (_Float16)o[qa][dt][r];
            *(half4*)(obase + 16 * dt) = pk;
        }
        if (g == 0) {
            int qt = (qbase + 16 * qa) >> 4;
            float* ml = ML + ((size_t)sp * QTILES + qt) * 32;
            ml[r16] = m[qa];
            ml[16 + r16] = l[qa];
        }
    }
}

// -------- kernel 3: merge the NS KV-split partials (16B loads, 8 elem/thr) --
template<int NS>
__global__ void merge_kernel(const ushort* __restrict__ Opb, const float* __restrict__ ML,
                             float* __restrict__ out) {
    int i = blockIdx.x * blockDim.x + threadIdx.x;
    int e = i * 8;
    if (e >= N_TOK * D) return;
    int q = e >> 7;
    int qt = q >> 4, qr = q & 15;
    float mv[NS], lv[NS];
    float M = -INFINITY;
    #pragma unroll
    for (int s = 0; s < NS; ++s) {
        const float* ml = ML + ((size_t)s * QTILES + qt) * 32;
        mv[s] = ml[qr];
        lv[s] = ml[16 + qr];
        M = fmaxf(M, mv[s]);
    }
    float L = 0.f, a[NS];
    #pragma unroll
    for (int s = 0; s < NS; ++s) { a[s] = __builtin_amdgcn_exp2f(mv[s] - M); L += a[s] * lv[s]; }
    float inv = 1.f / L;
    float acc[8];
    #pragma unroll
    for (int r = 0; r < 8; ++r) acc[r] = 0.f;
    #pragma unroll
    for (int s = 0; s < NS; ++s) {
        half8 ov = *(const half8*)(Opb + (size_t)s * N_TOK * D + e);
        #pragma unroll
        for (int r = 0; r < 8; ++r) acc[r] += (float)ov[r] * a[s];
    }
    f32x4 o0, o1;
    #pragma unroll
    for (int r = 0; r < 4; ++r) { o0[r] = acc[r] * inv; o1[r] = acc[4 + r] * inv; }
    *(f32x4*)(out + e) = o0;
    *(f32x4*)(out + e + 4) = o1;
}

extern "C" void kernel_launch(void* const* d_in, const int* in_sizes, int n_in,
                              void* d_out, int out_size, void* d_ws, size_t ws_size,
                              hipStream_t stream) {
    const float* X  = (const float*)d_in[0];
    const float* Wq = (const float*)d_in[1];
    const float* Wk = (const float*)d_in[2];
    const float* Wv = (const float*)d_in[3];
    float* out = (float*)d_out;

    char* ws = (char*)d_ws;
    ushort* Qh  = (ushort*)(ws);                   // 2 MB (f16, pre-scaled log2e)
    ushort* Kh  = (ushort*)(ws + 2097152);         // 2 MB (f16)
    ushort* Vt  = (ushort*)(ws + 4194304);         // 2 MB (f16, transposed)
    ushort* Opb = (ushort*)(ws + 6291456);         // NS * 2 MB (f16 partials)

    const size_t op_off = 6291456;
    const size_t need8 = op_off + (size_t)8 * N_TOK * D * 2 + (size_t)8 * QTILES * 32 * 4;

    proj_kernel<<<256, 256, 0, stream>>>(X, Wq, Wk, Wv, Qh, Kh, Vt);

    if (ws_size >= need8) {
        float* ML = (float*)(ws + op_off + (size_t)8 * N_TOK * D * 2);
        flash_kernel<8><<<(N_TOK / 128) * 8, 256, 0, stream>>>(Qh, Kh, Vt, Opb, ML);
        merge_kernel<8><<<(N_TOK * D / 8 + 255) / 256, 256, 0, stream>>>(Opb, ML, out);
    } else {
        float* ML = (float*)(ws + op_off + (size_t)4 * N_TOK * D * 2);
        flash_kernel<4><<<(N_TOK / 128) * 4, 256, 0, stream>>>(Qh, Kh, Vt, Opb, ML);
        merge_kernel<4><<<(N_TOK * D / 8 + 255) / 256, 256, 0, stream>>>(Opb, ML, out);
    }
}

// Round 24
// 68.626 us; speedup vs baseline: 1.1120x; 1.0026x over previous
//
#include <hip/hip_runtime.h>
#include <hip/hip_bf16.h>
#include <stdint.h>

#define N_TOK 8192
#define D 128
#define QTILES (N_TOK / 16)    // 512
#define KVB 64                 // kv rows per staged tile
#define KVTILES (N_TOK / KVB)  // 128
#define LOG2E 1.4426950408889634f

typedef __attribute__((ext_vector_type(8))) short short8;      // 8x16b frag
typedef __attribute__((ext_vector_type(4))) short short4v;     // 4x16b (8B)
typedef __attribute__((ext_vector_type(4))) float f32x4;       // MFMA accum
typedef __attribute__((ext_vector_type(8))) _Float16 half8;    // f16x8 frag
typedef __attribute__((ext_vector_type(4))) _Float16 half4;    // 4 f16 (8B)
typedef __attribute__((ext_vector_type(2))) __fp16 fp16x2;     // cvt_pkrtz ret
typedef __attribute__((ext_vector_type(2))) unsigned int uint2v;

__device__ __forceinline__ f32x4 zero4() {
    f32x4 z; z[0] = 0.f; z[1] = 0.f; z[2] = 0.f; z[3] = 0.f; return z;
}
__device__ __forceinline__ float ex2(float x) {
    return __builtin_amdgcn_exp2f(x);   // raw v_exp_f32 (2^x), no libm wrapper
}
__device__ __forceinline__ float max16(const f32x4* s) {
    // 16-value max via v_max3 fusion (nested triples)
    float a = fmaxf(fmaxf(s[0][0], s[0][1]), s[0][2]);
    float b = fmaxf(fmaxf(s[0][3], s[1][0]), s[1][1]);
    float c = fmaxf(fmaxf(s[1][2], s[1][3]), s[2][0]);
    float d = fmaxf(fmaxf(s[2][1], s[2][2]), s[2][3]);
    float e = fmaxf(fmaxf(s[3][0], s[3][1]), s[3][2]);
    return fmaxf(fmaxf(fmaxf(a, b), c), fmaxf(fmaxf(d, e), s[3][3]));
}

// ---- cross-lane 4-group reductions (lanes l, l^16, l^32, l^48) -------------
// gfx950 permlane{16,32}_swap are VALU (~4cy) vs shfl_xor's ds_swizzle.
#if __has_builtin(__builtin_amdgcn_permlane16_swap) && __has_builtin(__builtin_amdgcn_permlane32_swap)
__device__ __forceinline__ float red16_max(float x) {
    union { float f; unsigned u; } c; c.f = x;
    uint2v r = __builtin_amdgcn_permlane16_swap(c.u, c.u, false, false);
    union { unsigned u; float f; } a, b; a.u = r[0]; b.u = r[1];
    return fmaxf(a.f, b.f);
}
__device__ __forceinline__ float red32_max(float x) {
    union { float f; unsigned u; } c; c.f = x;
    uint2v r = __builtin_amdgcn_permlane32_swap(c.u, c.u, false, false);
    union { unsigned u; float f; } a, b; a.u = r[0]; b.u = r[1];
    return fmaxf(a.f, b.f);
}
__device__ __forceinline__ float red16_sum(float x) {
    union { float f; unsigned u; } c; c.f = x;
    uint2v r = __builtin_amdgcn_permlane16_swap(c.u, c.u, false, false);
    union { unsigned u; float f; } a, b; a.u = r[0]; b.u = r[1];
    return a.f + b.f;
}
__device__ __forceinline__ float red32_sum(float x) {
    union { float f; unsigned u; } c; c.f = x;
    uint2v r = __builtin_amdgcn_permlane32_swap(c.u, c.u, false, false);
    union { unsigned u; float f; } a, b; a.u = r[0]; b.u = r[1];
    return a.f + b.f;
}
#else
__device__ __forceinline__ float red16_max(float x) { return fmaxf(x, __shfl_xor(x, 16)); }
__device__ __forceinline__ float red32_max(float x) { return fmaxf(x, __shfl_xor(x, 32)); }
__device__ __forceinline__ float red16_sum(float x) { return x + __shfl_xor(x, 16); }
__device__ __forceinline__ float red32_sum(float x) { return x + __shfl_xor(x, 32); }
#endif

// load 8 consecutive f32 and convert to f16x8 fragment (RTN)
__device__ __forceinline__ half8 ld_f32_as_h8(const float* p) {
    f32x4 a = *(const f32x4*)(p);
    f32x4 b = *(const f32x4*)(p + 4);
    half8 w;
    #pragma unroll
    for (int j = 0; j < 4; ++j) {
        w[j] = (_Float16)a[j];
        w[4 + j] = (_Float16)b[j];
    }
    return w;
}

// -------- kernel 1: projections, single f16 MFMA, W converted in-register ---
// (R21-proven) 256 blocks x 4 waves; wave w handles jt in {2w, 2w+1}.
// Q pre-scaled by log2(e) so flash softmax runs in exp2 domain.
__global__ __launch_bounds__(256) void proj_kernel(
    const float* __restrict__ X, const float* __restrict__ Wq,
    const float* __restrict__ Wk, const float* __restrict__ Wv,
    ushort* __restrict__ Qh, ushort* __restrict__ Kh, ushort* __restrict__ Vt) {
    const int tid = threadIdx.x;
    const int lane = tid & 63;
    const int wid = tid >> 6;
    const int g = lane >> 4, r16 = lane & 15;
    const int qbase = blockIdx.x * 32;

    half8 xf[2][4];
    #pragma unroll
    for (int qa = 0; qa < 2; ++qa) {
        const float* xr = X + (size_t)(qbase + 16 * qa + r16) * D + 8 * g;
        #pragma unroll
        for (int ds = 0; ds < 4; ++ds)
            xf[qa][ds] = ld_f32_as_h8(xr + 32 * ds);
    }

    #pragma unroll
    for (int m = 0; m < 2; ++m) {
        const float* W = m ? Wk : Wq;
        ushort* O = m ? Kh : Qh;
        const float sc = m ? 1.0f : LOG2E;
        #pragma unroll
        for (int jj = 0; jj < 2; ++jj) {
            int jt = 2 * wid + jj;
            const float* wr = W + (size_t)(16 * jt + r16) * D + 8 * g;
            f32x4 acc[2] = {zero4(), zero4()};
            #pragma unroll
            for (int ds = 0; ds < 4; ++ds) {
                half8 wf = ld_f32_as_h8(wr + 32 * ds);
                #pragma unroll
                for (int qa = 0; qa < 2; ++qa)
                    acc[qa] = __builtin_amdgcn_mfma_f32_16x16x32_f16(wf, xf[qa][ds], acc[qa], 0, 0, 0);
            }
            #pragma unroll
            for (int qa = 0; qa < 2; ++qa) {
                half4 pk;
                #pragma unroll
                for (int r = 0; r < 4; ++r) pk[r] = (_Float16)(acc[qa][r] * sc);
                *(half4*)(O + (size_t)(qbase + 16 * qa + r16) * D + 16 * jt + 4 * g) = pk;
            }
        }
    }
    {
        #pragma unroll
        for (int jj = 0; jj < 2; ++jj) {
            int jt = 2 * wid + jj;
            const float* wr = Wv + (size_t)(16 * jt + r16) * D + 8 * g;
            f32x4 acc[2] = {zero4(), zero4()};
            #pragma unroll
            for (int ds = 0; ds < 4; ++ds) {
                half8 wf = ld_f32_as_h8(wr + 32 * ds);
                #pragma unroll
                for (int qa = 0; qa < 2; ++qa)
                    acc[qa] = __builtin_amdgcn_mfma_f32_16x16x32_f16(xf[qa][ds], wf, acc[qa], 0, 0, 0);
            }
            #pragma unroll
            for (int qa = 0; qa < 2; ++qa) {
                half4 pk;
                #pragma unroll
                for (int r = 0; r < 4; ++r) pk[r] = (_Float16)acc[qa][r];
                *(half4*)(Vt + (size_t)(16 * jt + r16) * N_TOK + qbase + 16 * qa + 4 * g) = pk;
            }
        }
    }
}

// -------- kernel 2: flash attention, double-buffered K+V LDS (R23 + peel) ---
// setprio kept (R21 A/B). permlane reductions kept (R23, -1.3us).
// NEW: l accumulated per-lane (single epilogue reduce; per-iter sum reduces
// removed) + final iteration peeled (no guards in the hot loop).
// 4 waves/block, 32 q-rows each. NS=8 -> sp == XCD id (L2-affine K/V).
template<int NS>
__global__ __launch_bounds__(256, 2) void flash_kernel(
    const ushort* __restrict__ Qh, const ushort* __restrict__ Kh,
    const ushort* __restrict__ Vt, ushort* __restrict__ Opb, float* __restrict__ ML) {
    __shared__ __align__(16) ushort K_lds[2][KVB * D];   // 2 x 16 KB f16
    __shared__ __align__(16) ushort V_lds[2][D * KVB];   // 2 x 16 KB f16
    __shared__ __align__(16) ushort P_lds[4 * 2048];     // 16 KB f16

    const int tid = threadIdx.x;
    const int lane = tid & 63;
    const int wid = tid >> 6;
    const int g = lane >> 4, r16 = lane & 15;
    const int sp = blockIdx.x % NS;        // == XCD id when NS==8
    const int qg = blockIdx.x / NS;
    const int nIter = KVTILES / NS;        // compile-time (KVTILES % NS == 0)
    const int t0 = sp * nIter;
    const int qbase = qg * 128 + wid * 32;
    const int pswz = (r16 & 7) << 3;

    half8 qf[2][4];
    #pragma unroll
    for (int qa = 0; qa < 2; ++qa) {
        const ushort* qr = Qh + (size_t)(qbase + 16 * qa + r16) * D + 8 * g;
        #pragma unroll
        for (int ds = 0; ds < 4; ++ds)
            qf[qa][ds] = *(const half8*)(qr + 32 * ds);
    }

    float m[2] = {-INFINITY, -INFINITY}, l[2] = {0.f, 0.f};   // l: per-LANE partial
    f32x4 o[2][8];
    #pragma unroll
    for (int qa = 0; qa < 2; ++qa)
        #pragma unroll
        for (int dt = 0; dt < 8; ++dt) o[qa][dt] = zero4();

    ushort* P_w = &P_lds[wid * 2048];

    short8 sk[4], sv[4];

    auto LOADT = [&](int it) {
        const int kv = it * KVB;
        #pragma unroll
        for (int rr = 0; rr < 4; ++rr) {
            int idx = tid + 256 * rr;              // [0,1024)
            int row = idx >> 4, seg = idx & 15;
            sk[rr] = *(const short8*)(Kh + (size_t)(kv + row) * D + seg * 8);
        }
        #pragma unroll
        for (int rr = 0; rr < 4; ++rr) {
            int idx = tid + 256 * rr;              // [0,1024)
            int row = idx >> 3, seg = idx & 7;
            sv[rr] = *(const short8*)(Vt + (size_t)row * N_TOK + kv + seg * 8);
        }
    };
    auto WRITET = [&](int b) {
        #pragma unroll
        for (int rr = 0; rr < 4; ++rr) {
            int idx = tid + 256 * rr;
            int row = idx >> 4, seg = idx & 15;
            *(short8*)&K_lds[b][(row * 128 + seg * 8) ^ ((row & 7) << 3)] = sk[rr];
        }
        #pragma unroll
        for (int rr = 0; rr < 4; ++rr) {
            int idx = tid + 256 * rr;
            int row = idx >> 3, seg = idx & 7;
            *(short8*)&V_lds[b][(row * 64 + seg * 8) ^ ((row & 7) << 3)] = sv[rr];
        }
    };

    auto COMPUTE = [&](int b) {
        const ushort* kb = K_lds[b];
        const ushort* vb = V_lds[b];

        // ---- S^T = K*Q^T (scores in log2 domain via Q pre-scaling)
        f32x4 s[2][4];
        #pragma unroll
        for (int qa = 0; qa < 2; ++qa)
            #pragma unroll
            for (int t = 0; t < 4; ++t) s[qa][t] = zero4();
        __builtin_amdgcn_s_setprio(1);
        #pragma unroll
        for (int t = 0; t < 4; ++t) {
            #pragma unroll
            for (int ds = 0; ds < 4; ++ds) {
                int row = 16 * t + r16;
                half8 kf = *(const half8*)&kb[(row * 128 + 32 * ds + 8 * g) ^ ((row & 7) << 3)];
                #pragma unroll
                for (int qa = 0; qa < 2; ++qa)
                    s[qa][t] = __builtin_amdgcn_mfma_f32_16x16x32_f16(kf, qf[qa][ds], s[qa][t], 0, 0, 0);
            }
        }
        __builtin_amdgcn_s_setprio(0);

        // ---- online softmax (exp2 domain; m per q-row; l is lane-partial)
        #pragma unroll
        for (int qa = 0; qa < 2; ++qa) {
            float tm = max16(s[qa]);
            tm = red16_max(tm);
            tm = red32_max(tm);
            // exact-skip rescale: when no lane's max grew, scale==1 for all
            if (!__all(tm <= m[qa])) {
                float mnew = fmaxf(m[qa], tm);
                float scale = ex2(m[qa] - mnew);
                l[qa] *= scale;       // lane-partial rescales identically
                #pragma unroll
                for (int dt = 0; dt < 8; ++dt) o[qa][dt] *= scale;
                m[qa] = mnew;
            }
            float psum = 0.f;
            #pragma unroll
            for (int t = 0; t < 4; ++t) {
                float p0 = ex2(s[qa][t][0] - m[qa]);
                float p1 = ex2(s[qa][t][1] - m[qa]);
                float p2 = ex2(s[qa][t][2] - m[qa]);
                float p3 = ex2(s[qa][t][3] - m[qa]);
                psum += (p0 + p1) + (p2 + p3);
                union { fp16x2 h[2]; short4v s4; } u;
                u.h[0] = __builtin_amdgcn_cvt_pkrtz(p0, p1);
                u.h[1] = __builtin_amdgcn_cvt_pkrtz(p2, p3);
                *(short4v*)&P_w[(qa * 1024 + r16 * 64 + 16 * t + 4 * g) ^ pswz] = u.s4;
            }
            l[qa] += psum;            // no cross-lane reduce here (epilogue)
        }

        // ---- O^T += V^T * P^T : 2 kv-chunks x 8 d-tiles (f16)
        __builtin_amdgcn_s_setprio(1);
        #pragma unroll
        for (int c = 0; c < 2; ++c) {
            half8 pf0 = *(const half8*)&P_w[(r16 * 64 + 32 * c + 8 * g) ^ pswz];
            half8 pf1 = *(const half8*)&P_w[(1024 + r16 * 64 + 32 * c + 8 * g) ^ pswz];
            #pragma unroll
            for (int dt = 0; dt < 8; ++dt) {
                int row = 16 * dt + r16;
                half8 vf = *(const half8*)&vb[(row * 64 + 32 * c + 8 * g) ^ ((row & 7) << 3)];
                o[0][dt] = __builtin_amdgcn_mfma_f32_16x16x32_f16(vf, pf0, o[0][dt], 0, 0, 0);
                o[1][dt] = __builtin_amdgcn_mfma_f32_16x16x32_f16(vf, pf1, o[1][dt], 0, 0, 0);
            }
        }
        __builtin_amdgcn_s_setprio(0);
    };

    LOADT(t0);
    WRITET(0);
    __syncthreads();

    int buf = 0;
    for (int ii = 0; ii < nIter - 1; ++ii) {   // hot loop: no guards
        LOADT(t0 + ii + 1);
        COMPUTE(buf);
        WRITET(buf ^ 1);
        __syncthreads();
        buf ^= 1;
    }
    COMPUTE(buf);                              // peeled final iteration

    // ---- epilogue: partial O (pre-division, f16) + (m[log2], l reduced once)
    #pragma unroll
    for (int qa = 0; qa < 2; ++qa) {
        float lt = red32_sum(red16_sum(l[qa]));
        ushort* obase = Opb + ((size_t)sp * N_TOK + qbase + 16 * qa + r16) * D + 4 * g;
        #pragma unroll
        for (int dt = 0; dt < 8; ++dt) {
            half4 pk;
            #pragma unroll
            for (int r = 0; r < 4; ++r) pk[r] = (_Float16)o[qa][dt][r];
            *(half4*)(obase + 16 * dt) = pk;
        }
        if (g == 0) {
            int qt = (qbase + 16 * qa) >> 4;
            float* ml = ML + ((size_t)sp * QTILES + qt) * 32;
            ml[r16] = m[qa];
            ml[16 + r16] = lt;
        }
    }
}

// -------- kernel 3: merge the NS KV-split partials (16B loads, 8 elem/thr) --
template<int NS>
__global__ void merge_kernel(const ushort* __restrict__ Opb, const float* __restrict__ ML,
                             float* __restrict__ out) {
    int i = blockIdx.x * blockDim.x + threadIdx.x;
    int e = i * 8;
    if (e >= N_TOK * D) return;
    int q = e >> 7;
    int qt = q >> 4, qr = q & 15;
    float mv[NS], lv[NS];
    float M = -INFINITY;
    #pragma unroll
    for (int s = 0; s < NS; ++s) {
        const float* ml = ML + ((size_t)s * QTILES + qt) * 32;
        mv[s] = ml[qr];
        lv[s] = ml[16 + qr];
        M = fmaxf(M, mv[s]);
    }
    float L = 0.f, a[NS];
    #pragma unroll
    for (int s = 0; s < NS; ++s) { a[s] = __builtin_amdgcn_exp2f(mv[s] - M); L += a[s] * lv[s]; }
    float inv = 1.f / L;
    float acc[8];
    #pragma unroll
    for (int r = 0; r < 8; ++r) acc[r] = 0.f;
    #pragma unroll
    for (int s = 0; s < NS; ++s) {
        half8 ov = *(const half8*)(Opb + (size_t)s * N_TOK * D + e);
        #pragma unroll
        for (int r = 0; r < 8; ++r) acc[r] += (float)ov[r] * a[s];
    }
    f32x4 o0, o1;
    #pragma unroll
    for (int r = 0; r < 4; ++r) { o0[r] = acc[r] * inv; o1[r] = acc[4 + r] * inv; }
    *(f32x4*)(out + e) = o0;
    *(f32x4*)(out + e + 4) = o1;
}

extern "C" void kernel_launch(void* const* d_in, const int* in_sizes, int n_in,
                              void* d_out, int out_size, void* d_ws, size_t ws_size,
                              hipStream_t stream) {
    const float* X  = (const float*)d_in[0];
    const float* Wq = (const float*)d_in[1];
    const float* Wk = (const float*)d_in[2];
    const float* Wv = (const float*)d_in[3];
    float* out = (float*)d_out;

    char* ws = (char*)d_ws;
    ushort* Qh  = (ushort*)(ws);                   // 2 MB (f16, pre-scaled log2e)
    ushort* Kh  = (ushort*)(ws + 2097152);         // 2 MB (f16)
    ushort* Vt  = (ushort*)(ws + 4194304);         // 2 MB (f16, transposed)
    ushort* Opb = (ushort*)(ws + 6291456);         // NS * 2 MB (f16 partials)

    const size_t op_off = 6291456;
    const size_t need8 = op_off + (size_t)8 * N_TOK * D * 2 + (size_t)8 * QTILES * 32 * 4;

    proj_kernel<<<256, 256, 0, stream>>>(X, Wq, Wk, Wv, Qh, Kh, Vt);

    if (ws_size >= need8) {
        float* ML = (float*)(ws + op_off + (size_t)8 * N_TOK * D * 2);
        flash_kernel<8><<<(N_TOK / 128) * 8, 256, 0, stream>>>(Qh, Kh, Vt, Opb, ML);
        merge_kernel<8><<<(N_TOK * D / 8 + 255) / 256, 256, 0, stream>>>(Opb, ML, out);
    } else {
        float* ML = (float*)(ws + op_off + (size_t)4 * N_TOK * D * 2);
        flash_kernel<4><<<(N_TOK / 128) * 4, 256, 0, stream>>>(Qh, Kh, Vt, Opb, ML);
        merge_kernel<4><<<(N_TOK * D / 8 + 255) / 256, 256, 0, stream>>>(Opb, ML, out);
    }
}